// Round 13
// baseline (478.155 us; speedup 1.0000x reference)
//
#include <hip/hip_runtime.h>
#include <hip/hip_cooperative_groups.h>
#include <stdint.h>

namespace cg = cooperative_groups;

typedef unsigned int u32;
typedef unsigned long long u64;

#define NCELLS  3872
#define NCLS    80
#define NFLAT   309760
#define NPRE    500
#define NPAD    512
#define HH      200
#define WW      304
#define NPIX    60800
#define NWORDS  950      // 60800 / 64 exactly
#define MSTRIDE 960
#define MAXOUT  100
#define OH      427
#define OW      640
#define MH      800
#define MW      1216
#define MAXG    4096
#define MAXPAIRS 16384
#define OUT_LBL 27328000
#define OUT_SCR 27328100
#define ROWS_PER_BLK 2
#define NRBLK 214        // ceil(427/2); 100*214 = 21400 = 8*2675

#define S_THR 0.1f
#define M_THR 0.005f
#define U_THR 0.001f

// ---------------- workspace layout (bytes) ----------------
#define OFF_HIST1   0u        // 65536 u32 (value-bins: bin = (int)(v*65536))
#define OFF_META    263168u   // 16 u32: [2]cutBin [3]gatherCnt [4]pairCnt
#define ZERO_BYTES  263232u
#define OFF_CAND    263424u   // 4096 u64
#define OFF_RAW     296192u   // 512 f32
#define OFF_LABEL   300288u
#define OFF_XIND    302336u
#define OFF_YIND    304384u
#define OFF_STRIDE  306432u
#define OFF_SMF     308480u
#define OFF_SCORE   310528u
#define OFF_LABELK  312576u
#define OFF_ORDER   314624u
#define OFF_SSCORE  316672u
#define OFF_TOPC    318720u   // 128 i32
#define OFF_PAIRI   319232u   // 16384 u32
#define OFF_PAIRIOU 384768u   // 16384 f32
#define OFF_W1YT0   450304u   // 800 i32
#define OFF_W1YA    453504u   // 800 f32
#define OFF_W1YB    456704u
#define OFF_W1XT0   459904u   // 1216 i32
#define OFF_W1XA    464768u
#define OFF_W1XB    469632u
#define OFF_W2YS    474496u   // 427 i32
#define OFF_W2YW    476224u   // 427*4 f32 (16B aligned)
#define OFF_W2XS    483072u   // 640 i32
#define OFF_W2XW    485632u   // 640*4 f32 (16B aligned)
#define OFF_MASKS   495872u   // 500*960 u64 (candidate-major, for pair-IoU)
#define OFF_MASKT   4335872u  // 950*512 u64 (word-major, coalesced writes)
#define OFF_PARTD   8227072u  // 950*512 f64 word partial sums
#define WS_NEED     12118272u

#define P_U32(off) ((u32*)(ws + (off)))
#define P_I32(off) ((int*)(ws + (off)))
#define P_F32(off) ((float*)(ws + (off)))
#define P_U64(off) ((u64*)(ws + (off)))

__device__ __forceinline__ void levelMeta(int loc, int& td, int& sd, int& ng, float& st) {
  if (loc < 1600)      { td = 0;    sd = 0;   ng = 40; st = 4.f;  }
  else if (loc < 2896) { td = 1600; sd = 40;  ng = 36; st = 8.f;  }
  else if (loc < 3472) { td = 2896; sd = 76;  ng = 24; st = 16.f; }
  else if (loc < 3728) { td = 3472; sd = 100; ng = 16; st = 32.f; }
  else                 { td = 3728; sd = 116; ng = 12; st = 64.f; }
}

// value bin: exact & monotone for positive f32
__device__ __forceinline__ u32 vbin(float v) {
  int b = (int)(v * 65536.0f);
  if (b > 65535) b = 65535;
  if (b < 0) b = 0;
  return (u32)b;
}

__device__ __forceinline__ u64 shflx64(u64 v, int m) {
  u32 lo = (u32)v, hi = (u32)(v >> 32);
  lo = (u32)__shfl_xor((int)lo, m);
  hi = (u32)__shfl_xor((int)hi, m);
  return (((u64)hi) << 32) | lo;
}

// sort body shared by coopA/standalone: hybrid bitonic over 512 regs (block-local)
__device__ __forceinline__ u64 bitonic512(u64 key, int tid, u64* sk) {
  for (int k = 2; k <= NPAD; k <<= 1) {
    for (int j = k >> 1; j > 0; j >>= 1) {
      bool up = ((tid & k) == 0);
      u64 other;
      if (j < 64) {
        other = shflx64(key, j);
      } else {
        sk[tid] = key;
        __syncthreads();
        other = sk[tid ^ j];
        __syncthreads();
      }
      bool takeMax = (((tid & j) == 0) == up);
      key = takeMax ? (key > other ? key : other) : (key < other ? key : other);
    }
  }
  return key;
}

// candidate metadata + resize weight tables (block 0, 512 threads)
__device__ void selwTail(char* ws, const u64* skSorted, int G, int tid) {
  {
    float rawv = -1.f; int lab = -1, xi = 0, yi = 0; float st = 3.0e38f;
    if (tid < NPRE && tid < G) {
      u64 key = skSorted[tid];
      u32 b = (u32)(key >> 32);
      u32 idx = ~((u32)(key & 0xffffffffu));
      rawv = __uint_as_float(b);
      int loc = (int)(idx / (u32)NCLS);
      lab = (int)(idx - (u32)loc * NCLS);
      int td, sd, ng; levelMeta(loc, td, sd, ng, st);
      int rel = loc - td;
      int row = rel / ng;
      yi = row + sd;
      xi = (rel - row * ng) + sd;
    }
    P_F32(OFF_RAW)[tid] = rawv;
    P_I32(OFF_LABEL)[tid] = lab;
    P_I32(OFF_XIND)[tid] = xi;
    P_I32(OFF_YIND)[tid] = yi;
    P_F32(OFF_STRIDE)[tid] = st;
    P_F32(OFF_SCORE)[tid] = 0.f;
    P_I32(OFF_LABELK)[tid] = -1;
    P_F32(OFF_SMF)[tid] = 0.f;
  }
  int t = tid;
  for (int r = t; r < MH; r += 512) {
    float s1 = ((float)r + 0.5f) * 0.25f - 0.5f;
    int t0 = (int)floorf(s1);
    float f = s1 - (float)t0;
    float wa = 1.f - f, wb = f;
    bool ia = (t0 >= 0) && (t0 < HH);
    bool ib = ((t0 + 1) >= 0) && ((t0 + 1) < HH);
    float tw = (ia ? wa : 0.f) + (ib ? wb : 0.f);
    float na = ia ? (wa / tw) : 0.f;
    float nb = ib ? (wb / tw) : 0.f;
    int base; float A, B;
    if (t0 < 0) { base = 0; A = nb; B = 0.f; }
    else if (t0 >= HH - 1) { base = HH - 2; A = 0.f; B = na; }
    else { base = t0; A = na; B = nb; }
    P_I32(OFF_W1YT0)[r] = base;
    P_F32(OFF_W1YA)[r] = A;
    P_F32(OFF_W1YB)[r] = B;
  }
  for (int c = t; c < MW; c += 512) {
    float s1 = ((float)c + 0.5f) * 0.25f - 0.5f;
    int t0 = (int)floorf(s1);
    float f = s1 - (float)t0;
    float wa = 1.f - f, wb = f;
    bool ia = (t0 >= 0) && (t0 < WW);
    bool ib = ((t0 + 1) >= 0) && ((t0 + 1) < WW);
    float tw = (ia ? wa : 0.f) + (ib ? wb : 0.f);
    float na = ia ? (wa / tw) : 0.f;
    float nb = ib ? (wb / tw) : 0.f;
    int base; float A, B;
    if (t0 < 0) { base = 0; A = nb; B = 0.f; }
    else if (t0 >= WW - 1) { base = WW - 2; A = 0.f; B = na; }
    else { base = t0; A = na; B = nb; }
    P_I32(OFF_W1XT0)[c] = base;
    P_F32(OFF_W1XA)[c] = A;
    P_F32(OFF_W1XB)[c] = B;
  }
  for (int o = t; o < OH; o += 512) {
    const float inv = (float)(800.0 / 427.0);
    float s2 = ((float)o + 0.5f) * inv - 0.5f;
    int rA = (int)ceilf(s2 - inv);
    int rB = (int)floorf(s2 + inv);
    if (rA < 0) rA = 0;
    if (rB > MH - 1) rB = MH - 1;
    float tot = 0.f;
    for (int r = rA; r <= rB; r++) {
      float x = fabsf(s2 - (float)r) / inv;
      float w = 1.f - x; if (w < 0.f) w = 0.f;
      tot += w;
    }
    int base = rA; if (base > MH - 4) base = MH - 4;
    float o4[4] = {0.f, 0.f, 0.f, 0.f};
    for (int r = rA; r <= rB; r++) {
      float x = fabsf(s2 - (float)r) / inv;
      float w = 1.f - x; if (w < 0.f) w = 0.f;
      o4[r - base] += w / tot;
    }
    P_I32(OFF_W2YS)[o] = base;
    float* wp = P_F32(OFF_W2YW) + o * 4;
    wp[0] = o4[0]; wp[1] = o4[1]; wp[2] = o4[2]; wp[3] = o4[3];
  }
  for (int o = t; o < OW; o += 512) {
    const float inv = (float)(1216.0 / 640.0);
    float s2 = ((float)o + 0.5f) * inv - 0.5f;
    int rA = (int)ceilf(s2 - inv);
    int rB = (int)floorf(s2 + inv);
    if (rA < 0) rA = 0;
    if (rB > MW - 1) rB = MW - 1;
    float tot = 0.f;
    for (int r = rA; r <= rB; r++) {
      float x = fabsf(s2 - (float)r) / inv;
      float w = 1.f - x; if (w < 0.f) w = 0.f;
      tot += w;
    }
    int base = rA; if (base > MW - 4) base = MW - 4;
    float o4[4] = {0.f, 0.f, 0.f, 0.f};
    for (int r = rA; r <= rB; r++) {
      float x = fabsf(s2 - (float)r) / inv;
      float w = 1.f - x; if (w < 0.f) w = 0.f;
      o4[r - base] += w / tot;
    }
    P_I32(OFF_W2XS)[o] = base;
    float* wp = P_F32(OFF_W2XW) + o * 4;
    wp[0] = o4[0]; wp[1] = o4[1]; wp[2] = o4[2]; wp[3] = o4[3];
  }
}

// -------- cooperative A: histogram -> cut-scan -> gather -> top-500 + tables --------
__global__ __launch_bounds__(512) void kcoopA(const float* __restrict__ cate, char* __restrict__ ws) {
  cg::grid_group grid = cg::this_grid();
  __shared__ u64 sk[MAXG];
  __shared__ u32 cs[512];
  __shared__ u32 sfx[512];
  __shared__ int cbS;
  __shared__ u32 aboveS;
  int tid = threadIdx.x;
  int gtid = blockIdx.x * 512 + tid;
  int gstride = gridDim.x * 512;
  u32* h = P_U32(OFF_HIST1);
  const float4* cate4 = (const float4*)cate;
  // phase 1: histogram
  for (int i = gtid; i < NFLAT / 4; i += gstride) {
    float4 v = cate4[i];
    if (v.x > S_THR) atomicAdd(&h[vbin(v.x)], 1u);
    if (v.y > S_THR) atomicAdd(&h[vbin(v.y)], 1u);
    if (v.z > S_THR) atomicAdd(&h[vbin(v.z)], 1u);
    if (v.w > S_THR) atomicAdd(&h[vbin(v.w)], 1u);
  }
  grid.sync();
  // phase 2: cut-bin scan (block 0)
  if (blockIdx.x == 0) {
    u32 s = 0;
    for (int b = 0; b < 128; b++) s += h[tid * 128 + b];
    sfx[tid] = s;
    if (tid == 0) cbS = -1;
    __syncthreads();
    for (int off = 1; off < 512; off <<= 1) {
      u32 v = (tid + off < 512) ? sfx[tid + off] : 0u;
      __syncthreads();
      sfx[tid] += v;
      __syncthreads();
    }
    u32 nxt = (tid < 511) ? sfx[tid + 1] : 0u;
    if (sfx[tid] >= NPRE && nxt < NPRE) { cbS = tid; aboveS = nxt; }
    __syncthreads();
    u32* meta = P_U32(OFF_META);
    if (cbS < 0) {
      if (tid == 0) meta[2] = 0u;
    } else {
      int cb = cbS;
      if (tid < 128) cs[tid] = h[cb * 128 + tid];
      __syncthreads();
      if (tid == 0) {
        u32 cum = aboveS;
        u32 bin = (u32)(cb * 128);
        for (int b = 127; b >= 0; b--) {
          u32 hb = cs[b];
          if (cum + hb >= NPRE) { bin = (u32)(cb * 128 + b); break; }
          cum += hb;
        }
        meta[2] = bin;
      }
    }
  }
  grid.sync();
  // phase 3: gather
  u32 key = P_U32(OFF_META)[2];
  u64* cand = P_U64(OFF_CAND);
  u32* cntp = &P_U32(OFF_META)[3];
  for (int i = gtid; i < NFLAT / 4; i += gstride) {
    float4 v = cate4[i];
    #pragma unroll
    for (int q = 0; q < 4; q++) {
      float f = (q == 0) ? v.x : (q == 1) ? v.y : (q == 2) ? v.z : v.w;
      if (f > S_THR && vbin(f) >= key) {
        u32 pos = atomicAdd(cntp, 1u);
        if (pos < MAXG) cand[pos] = (((u64)__float_as_uint(f)) << 32) | (u32)(~(u32)(i * 4 + q));
      }
    }
  }
  grid.sync();
  // phase 4: top-500 sort + metadata + weight tables (block 0)
  if (blockIdx.x == 0) {
    int G = (int)P_U32(OFF_META)[3]; if (G > MAXG) G = MAXG;
    int n = NPAD;
    while (n < G) n <<= 1;
    if (n == NPAD) {
      u64 k0 = (tid < G) ? cand[tid] : 0ull;
      k0 = bitonic512(k0, tid, sk);
      sk[tid] = k0;
      __syncthreads();
    } else {
      for (int i = tid; i < n; i += 512) sk[i] = (i < G) ? cand[i] : 0ull;
      __syncthreads();
      for (int k = 2; k <= n; k <<= 1) {
        for (int j = k >> 1; j > 0; j >>= 1) {
          for (int i = tid; i < n; i += 512) {
            int l = i ^ j;
            if (l > i) {
              u64 a = sk[i], b = sk[l];
              bool sw = ((i & k) == 0) ? (a < b) : (a > b);
              if (sw) { sk[i] = b; sk[l] = a; }
            }
          }
          __syncthreads();
        }
      }
    }
    selwTail(ws, sk, G, tid);
  }
}

// -------- stage 2: word-major mask build, one candidate per THREAD --------
__global__ __launch_bounds__(256) void kmaskA(const float* __restrict__ segx, const float* __restrict__ segy,
                                              char* __restrict__ ws) {
  __shared__ float lx[128 * 64];
  __shared__ float ly[128 * 64];
  int w0 = blockIdx.x;
  int base = w0 << 6;
  int tid = threadIdx.x;
  for (int idx = tid; idx < 128 * 64; idx += 256) {
    int r = idx >> 6, col = idx & 63;
    int sw = col ^ (r & 63);              // XOR swizzle: distinct banks per row
    lx[(r << 6) + sw] = segx[(size_t)r * NPIX + base + col];
    ly[(r << 6) + sw] = segy[(size_t)r * NPIX + base + col];
  }
  __syncthreads();
  const int* xind = P_I32(OFF_XIND);
  const int* yind = P_I32(OFF_YIND);
  u64* maskT = P_U64(OFF_MASKT) + (size_t)w0 * NPAD;
  double* partD = (double*)(ws + OFF_PARTD) + (size_t)w0 * NPAD;
  for (int c = tid; c < NPRE; c += 256) {
    int xi = xind[c], yi = yind[c];
    const float* rx = &lx[xi << 6];
    const float* ry = &ly[yi << 6];
    int xk = xi & 63, yk = yi & 63;
    u32 lo = 0, hi = 0;
    double sum = 0.0;
    #pragma unroll 8
    for (int p = 0; p < 32; p++) {
      float s = rx[p ^ xk] * ry[p ^ yk];
      if (s > M_THR) { lo |= (1u << p); sum += (double)s; }
    }
    #pragma unroll 8
    for (int p = 32; p < 64; p++) {
      float s = rx[p ^ xk] * ry[p ^ yk];
      if (s > M_THR) { hi |= (1u << (p - 32)); sum += (double)s; }
    }
    maskT[c] = (((u64)hi) << 32) | lo;
    partD[c] = sum;
  }
}

// -------- cooperative B: maskBT -> sort+pairs -> pair IoU -> matrix-NMS --------
__global__ __launch_bounds__(512) void kcoopB(char* __restrict__ ws, float* __restrict__ out) {
  cg::grid_group grid = cg::this_grid();
  __shared__ u64 tile[64][65];
  __shared__ double cd[512];
  __shared__ int ci[512];
  __shared__ u64 sk[NPAD];
  __shared__ short slab[NPAD];
  __shared__ u32 scan[NPAD];
  __shared__ int compI[NPAD];
  __shared__ int coefI[NPAD];
  int tid = threadIdx.x;
  int bid = blockIdx.x;
  const u64* maskT = P_U64(OFF_MASKT);
  // phase 1: per-candidate reduction (blocks 0..499) / transpose (500..619)
  if (bid < NPRE) {
    int c = bid;
    const double* partD = (const double*)(ws + OFF_PARTD);
    double ds = 0.0; int cnt = 0;
    for (int w = tid; w < NWORDS; w += 512) {
      ds += partD[(size_t)w * NPAD + c];
      cnt += (int)__popcll(maskT[(size_t)w * NPAD + c]);
    }
    cd[tid] = ds; ci[tid] = cnt;
    __syncthreads();
    for (int s2 = 256; s2 > 0; s2 >>= 1) {
      if (tid < s2) { ci[tid] += ci[tid + s2]; cd[tid] += cd[tid + s2]; }
      __syncthreads();
    }
    if (tid == 0) {
      float sm = (float)ci[0];
      float rawv = P_F32(OFF_RAW)[c];
      bool valid = rawv > S_THR;
      bool keep = valid && (sm > P_F32(OFF_STRIDE)[c]);
      float ssf = (float)cd[0];
      float segsc = ssf / fmaxf(sm, 1e-6f);
      P_F32(OFF_SCORE)[c] = keep ? (rawv * segsc) : 0.f;
      P_F32(OFF_SMF)[c] = keep ? sm : 0.f;
      P_I32(OFF_LABELK)[c] = keep ? P_I32(OFF_LABEL)[c] : -1;
    }
  } else {
    int q = bid - NPRE;                 // 0..119 = 15 x 8 tiles
    int w0 = (q % 15) << 6;
    int c0 = (q / 15) << 6;
    for (int idx = tid; idx < 64 * 64; idx += 512) {
      int rw = idx >> 6, cc = idx & 63;
      int w = w0 + rw;
      tile[rw][cc] = (w < NWORDS) ? maskT[(size_t)w * NPAD + (c0 + cc)] : 0ull;
    }
    __syncthreads();
    u64* masks = P_U64(OFF_MASKS);
    for (int idx = tid; idx < 64 * 64; idx += 512) {
      int rc = idx >> 6, wwi = idx & 63;
      int c = c0 + rc, w = w0 + wwi;
      if (c < NPRE && w < NWORDS) masks[(size_t)c * MSTRIDE + w] = tile[wwi][rc];
    }
  }
  grid.sync();
  // phase 2: descending sort + same-class pair list (block 0)
  if (bid == 0) {
    float sc = (tid < NPRE) ? P_F32(OFF_SCORE)[tid] : 0.f;
    u64 key = (((u64)__float_as_uint(sc)) << 32) | (u32)(NPAD - 1 - tid);
    key = bitonic512(key, tid, sk);
    int ord = NPAD - 1 - (int)(key & 0xffffffffu);
    P_I32(OFF_ORDER)[tid] = ord;
    P_F32(OFF_SSCORE)[tid] = __uint_as_float((u32)(key >> 32));
    const int* labelK = P_I32(OFF_LABELK);
    int lab = (tid < NPRE) ? labelK[ord] : -1;
    slab[tid] = (short)lab;
    __syncthreads();
    u32 cnt = 0;
    if (lab >= 0) {
      short lj = (short)lab;
      for (int i = 0; i < tid; i++) if (slab[i] == lj) cnt++;
    }
    scan[tid] = cnt;
    __syncthreads();
    for (int off = 1; off < NPAD; off <<= 1) {
      u32 v = (tid >= off) ? scan[tid - off] : 0u;
      __syncthreads();
      scan[tid] += v;
      __syncthreads();
    }
    if (tid == NPAD - 1) {
      u32 tot = scan[tid];
      P_U32(OFF_META)[4] = (tot > MAXPAIRS) ? MAXPAIRS : tot;
    }
    if (lab >= 0 && cnt) {
      u32 pos = scan[tid] - cnt;
      short lj = (short)lab;
      u32* pairI = P_U32(OFF_PAIRI);
      for (int i = 0; i < tid; i++) {
        if (slab[i] == lj) {
          if (pos < MAXPAIRS) pairI[pos] = (((u32)i) << 16) | (u32)tid;
          pos++;
        }
      }
    }
  }
  grid.sync();
  // phase 3: pair IoU (one wave per pair, all blocks)
  {
    int P = (int)P_U32(OFF_META)[4]; if (P > MAXPAIRS) P = MAXPAIRS;
    const int* order = P_I32(OFF_ORDER);
    const float* smf = P_F32(OFF_SMF);
    const u64* masks = P_U64(OFF_MASKS);
    int wid = tid >> 6, lane = tid & 63;
    int gw = bid * 8 + wid;
    int gwstride = gridDim.x * 8;
    for (int p = gw; p < P; p += gwstride) {
      u32 ij = P_U32(OFF_PAIRI)[p];
      int oi = order[ij >> 16];
      int oj = order[ij & 0xffffu];
      const u64* mi = masks + (size_t)oi * MSTRIDE;
      const u64* mj = masks + (size_t)oj * MSTRIDE;
      int inter = 0;
      for (int w = lane; w < NWORDS; w += 64)
        inter += (int)__popcll(mi[w] & mj[w]);
      for (int off = 32; off > 0; off >>= 1)
        inter += __shfl_down(inter, off);
      if (lane == 0) {
        float fi = (float)inter;
        float uni = (smf[oj] + smf[oi]) - fi;
        float iou = (uni > 0.f) ? (fi / fmaxf(uni, 1e-12f)) : 0.f;
        P_F32(OFF_PAIRIOU)[p] = iou;
      }
    }
  }
  grid.sync();
  // phase 4: matrix-NMS decay + top-100 (block 0)
  if (bid == 0) {
    int P = (int)P_U32(OFF_META)[4]; if (P > MAXPAIRS) P = MAXPAIRS;
    const u32* pairI = P_U32(OFF_PAIRI);
    const float* pairIou = P_F32(OFF_PAIRIOU);
    const float* sscore = P_F32(OFF_SSCORE);
    const int* order = P_I32(OFF_ORDER);
    const int* labelK = P_I32(OFF_LABELK);
    int* topc = P_I32(OFF_TOPC);
    compI[tid] = 0;
    coefI[tid] = __float_as_int(1.0f);
    __syncthreads();
    for (int p = tid; p < P; p += 512) {
      int j = (int)(pairI[p] & 0xffffu);
      atomicMax(&compI[j], __float_as_int(pairIou[p]));
    }
    __syncthreads();
    for (int p = tid; p < P; p += 512) {
      u32 ij = pairI[p];
      int i = (int)(ij >> 16), j = (int)(ij & 0xffffu);
      float x = pairIou[p];
      float c = __int_as_float(compI[i]);
      float x2 = x * x, c2 = c * c;
      float r = (float)exp(-2.0 * ((double)x2 - (double)c2));
      atomicMin(&coefI[j], __float_as_int(r));
    }
    __syncthreads();
    float ns = 0.f;
    if (tid < NPRE) {
      ns = sscore[tid] * __int_as_float(coefI[tid]);
      ns = (ns > U_THR) ? ns : 0.f;
    }
    u64 key = (((u64)__float_as_uint(ns)) << 32) | (u32)(NPAD - 1 - tid);
    key = bitonic512(key, tid, sk);
    if (tid < MAXOUT) {
      int pos = NPAD - 1 - (int)(key & 0xffffffffu);
      int cand = order[pos];
      topc[tid] = cand;
      out[OUT_LBL + tid] = (float)labelK[cand];
      out[OUT_SCR + tid] = __uint_as_float((u32)(key >> 32));
    }
  }
}

// -------- fallback (small ws): candidate-major mask + standalone chain --------
__global__ __launch_bounds__(256) void kmask(const float* __restrict__ segx, const float* __restrict__ segy,
                                             char* __restrict__ ws) {
  int c = blockIdx.x;
  int tid = threadIdx.x;
  int lane = tid & 63, wv = tid >> 6;
  const float* X = segx + (size_t)P_I32(OFF_XIND)[c] * NPIX;
  const float* Y = segy + (size_t)P_I32(OFF_YIND)[c] * NPIX;
  u64* mrow = P_U64(OFF_MASKS) + (size_t)c * MSTRIDE;
  int cnt = 0;
  double ssum = 0.0;
  for (int w0 = wv; w0 < NWORDS; w0 += 4) {
    int p = (w0 << 6) + lane;
    float s = X[p] * Y[p];
    bool b = s > M_THR;
    u64 bal = __ballot(b ? 1 : 0);
    if (lane == 0) mrow[w0] = bal;
    if (b) { cnt++; ssum += (double)s; }
  }
  __shared__ int ci[256];
  __shared__ double cd[256];
  ci[tid] = cnt; cd[tid] = ssum;
  __syncthreads();
  for (int s2 = 128; s2 > 0; s2 >>= 1) {
    if (tid < s2) { ci[tid] += ci[tid + s2]; cd[tid] += cd[tid + s2]; }
    __syncthreads();
  }
  if (tid == 0) {
    float sm = (float)ci[0];
    float rawv = P_F32(OFF_RAW)[c];
    bool valid = rawv > S_THR;
    bool keep = valid && (sm > P_F32(OFF_STRIDE)[c]);
    float ssf = (float)cd[0];
    float segsc = ssf / fmaxf(sm, 1e-6f);
    P_F32(OFF_SCORE)[c] = keep ? (rawv * segsc) : 0.f;
    P_F32(OFF_SMF)[c] = keep ? sm : 0.f;
    P_I32(OFF_LABELK)[c] = keep ? P_I32(OFF_LABEL)[c] : -1;
  }
}

__global__ __launch_bounds__(512) void ksp(char* __restrict__ ws) {
  __shared__ u64 sk[NPAD];
  __shared__ short slab[NPAD];
  __shared__ u32 scan[NPAD];
  int t = threadIdx.x;
  float sc = (t < NPRE) ? P_F32(OFF_SCORE)[t] : 0.f;
  u64 key = (((u64)__float_as_uint(sc)) << 32) | (u32)(NPAD - 1 - t);
  key = bitonic512(key, t, sk);
  int ord = NPAD - 1 - (int)(key & 0xffffffffu);
  P_I32(OFF_ORDER)[t] = ord;
  P_F32(OFF_SSCORE)[t] = __uint_as_float((u32)(key >> 32));
  const int* labelK = P_I32(OFF_LABELK);
  int lab = (t < NPRE) ? labelK[ord] : -1;
  slab[t] = (short)lab;
  __syncthreads();
  u32 cnt = 0;
  if (lab >= 0) {
    short lj = (short)lab;
    for (int i = 0; i < t; i++) if (slab[i] == lj) cnt++;
  }
  scan[t] = cnt;
  __syncthreads();
  for (int off = 1; off < NPAD; off <<= 1) {
    u32 v = (t >= off) ? scan[t - off] : 0u;
    __syncthreads();
    scan[t] += v;
    __syncthreads();
  }
  if (t == NPAD - 1) {
    u32 tot = scan[t];
    P_U32(OFF_META)[4] = (tot > MAXPAIRS) ? MAXPAIRS : tot;
  }
  if (lab >= 0 && cnt) {
    u32 pos = scan[t] - cnt;
    short lj = (short)lab;
    u32* pairI = P_U32(OFF_PAIRI);
    for (int i = 0; i < t; i++) {
      if (slab[i] == lj) {
        if (pos < MAXPAIRS) pairI[pos] = (((u32)i) << 16) | (u32)t;
        pos++;
      }
    }
  }
}

__global__ __launch_bounds__(64) void kpiou(char* __restrict__ ws) {
  int P = (int)P_U32(OFF_META)[4]; if (P > MAXPAIRS) P = MAXPAIRS;
  const int* order = P_I32(OFF_ORDER);
  const float* smf = P_F32(OFF_SMF);
  const u64* masks = P_U64(OFF_MASKS);
  for (int p = blockIdx.x; p < P; p += gridDim.x) {
    u32 ij = P_U32(OFF_PAIRI)[p];
    int oi = order[ij >> 16];
    int oj = order[ij & 0xffffu];
    const u64* mi = masks + (size_t)oi * MSTRIDE;
    const u64* mj = masks + (size_t)oj * MSTRIDE;
    int inter = 0;
    for (int w = threadIdx.x; w < NWORDS; w += 64)
      inter += (int)__popcll(mi[w] & mj[w]);
    for (int off = 32; off > 0; off >>= 1)
      inter += __shfl_down(inter, off);
    if (threadIdx.x == 0) {
      float fi = (float)inter;
      float uni = (smf[oj] + smf[oi]) - fi;
      float iou = (uni > 0.f) ? (fi / fmaxf(uni, 1e-12f)) : 0.f;
      P_F32(OFF_PAIRIOU)[p] = iou;
    }
  }
}

__global__ __launch_bounds__(512) void knms(char* __restrict__ ws, float* __restrict__ out) {
  __shared__ int compI[NPAD];
  __shared__ int coefI[NPAD];
  __shared__ u64 sk[NPAD];
  int t = threadIdx.x;
  int P = (int)P_U32(OFF_META)[4]; if (P > MAXPAIRS) P = MAXPAIRS;
  const u32* pairI = P_U32(OFF_PAIRI);
  const float* pairIou = P_F32(OFF_PAIRIOU);
  const float* sscore = P_F32(OFF_SSCORE);
  const int* order = P_I32(OFF_ORDER);
  const int* labelK = P_I32(OFF_LABELK);
  int* topc = P_I32(OFF_TOPC);
  compI[t] = 0;
  coefI[t] = __float_as_int(1.0f);
  __syncthreads();
  for (int p = t; p < P; p += 512) {
    int j = (int)(pairI[p] & 0xffffu);
    atomicMax(&compI[j], __float_as_int(pairIou[p]));
  }
  __syncthreads();
  for (int p = t; p < P; p += 512) {
    u32 ij = pairI[p];
    int i = (int)(ij >> 16), j = (int)(ij & 0xffffu);
    float x = pairIou[p];
    float c = __int_as_float(compI[i]);
    float x2 = x * x, c2 = c * c;
    float r = (float)exp(-2.0 * ((double)x2 - (double)c2));
    atomicMin(&coefI[j], __float_as_int(r));
  }
  __syncthreads();
  float ns = 0.f;
  if (t < NPRE) {
    ns = sscore[t] * __int_as_float(coefI[t]);
    ns = (ns > U_THR) ? ns : 0.f;
  }
  u64 key = (((u64)__float_as_uint(ns)) << 32) | (u32)(NPAD - 1 - t);
  key = bitonic512(key, t, sk);
  if (t < MAXOUT) {
    int pos = NPAD - 1 - (int)(key & 0xffffffffu);
    int cand = order[pos];
    topc[t] = cand;
    out[OUT_LBL + t] = (float)labelK[cand];
    out[OUT_SCR + t] = __uint_as_float((u32)(key >> 32));
  }
}

// -------- stage 7: fused double-resize + binarize; register stage-1 --------
__global__ __launch_bounds__(256) void kout(const float* __restrict__ segx, const float* __restrict__ segy,
                                            char* __restrict__ ws, float* __restrict__ out) {
  __shared__ float t1s[6][WW];   // y-interp mid rows
  __shared__ float yrs[2][MW];   // per-out-row y-contracted mid columns
  int flat = blockIdx.x;
  int w = (flat & 7) * 2675 + (flat >> 3);   // bijective XCD swizzle (21400 = 8*2675)
  int kk = w / NRBLK;
  int r2 = w - kk * NRBLK;
  int oy0 = r2 * ROWS_PER_BLK;
  int nrow = (oy0 + 1 < OH) ? 2 : 1;
  int tid = threadIdx.x;
  int cand = P_I32(OFF_TOPC)[kk];
  const float* X = segx + (size_t)P_I32(OFF_XIND)[cand] * NPIX;
  const float* Y = segy + (size_t)P_I32(OFF_YIND)[cand] * NPIX;
  const int* w2ys = P_I32(OFF_W2YS);
  int rb = w2ys[oy0];
  const int* w1yT0 = P_I32(OFF_W1YT0);
  const float* w1yA = P_F32(OFF_W1YA);
  const float* w1yB = P_F32(OFF_W1YB);
  int smin = w1yT0[rb];
  float Ay[6], By[6]; int i0a[6];
  #pragma unroll
  for (int mr = 0; mr < 6; mr++) {
    int r = rb + mr; if (r > MH - 1) r = MH - 1;
    i0a[mr] = w1yT0[r] - smin;
    Ay[mr] = w1yA[r];
    By[mr] = w1yB[r];
  }
  {
    int r0 = smin;     if (r0 > HH - 1) r0 = HH - 1;
    int r1 = smin + 1; if (r1 > HH - 1) r1 = HH - 1;
    int r2s = smin + 2; if (r2s > HH - 1) r2s = HH - 1;
    int r3 = smin + 3; if (r3 > HH - 1) r3 = HH - 1;
    const float* X0 = X + r0 * WW; const float* Y0 = Y + r0 * WW;
    const float* X1 = X + r1 * WW; const float* Y1 = Y + r1 * WW;
    const float* X2 = X + r2s * WW; const float* Y2 = Y + r2s * WW;
    const float* X3 = X + r3 * WW; const float* Y3 = Y + r3 * WW;
    for (int u = tid; u < WW; u += 256) {
      float s0 = X0[u] * Y0[u];
      float s1 = X1[u] * Y1[u];
      float s2 = X2[u] * Y2[u];
      float s3 = X3[u] * Y3[u];
      #pragma unroll
      for (int mr = 0; mr < 6; mr++) {
        int i0 = i0a[mr];
        float sa, sb;
        if (i0 == 0)      { sa = s0; sb = s1; }
        else if (i0 == 1) { sa = s1; sb = s2; }
        else              { sa = s2; sb = s3; }
        t1s[mr][u] = fmaf(By[mr], sb, Ay[mr] * sa);
      }
    }
  }
  __syncthreads();
  const int* w1xT0 = P_I32(OFF_W1XT0);
  const float* w1xA = P_F32(OFF_W1XA);
  const float* w1xB = P_F32(OFF_W1XB);
  float4 wy0 = *(const float4*)(P_F32(OFF_W2YW) + oy0 * 4);
  int oy1 = (nrow == 2) ? (oy0 + 1) : oy0;
  float4 wy1 = *(const float4*)(P_F32(OFF_W2YW) + oy1 * 4);
  int off1 = w2ys[oy1] - rb;
  for (int cc = tid; cc < MW; cc += 256) {
    int u0 = w1xT0[cc];
    float xa = w1xA[cc], xb = w1xB[cc];
    float up0 = fmaf(xb, t1s[0][u0 + 1], xa * t1s[0][u0]);
    float up1 = fmaf(xb, t1s[1][u0 + 1], xa * t1s[1][u0]);
    float up2 = fmaf(xb, t1s[2][u0 + 1], xa * t1s[2][u0]);
    float up3 = fmaf(xb, t1s[3][u0 + 1], xa * t1s[3][u0]);
    float up4 = fmaf(xb, t1s[4][u0 + 1], xa * t1s[4][u0]);
    float up5 = fmaf(xb, t1s[5][u0 + 1], xa * t1s[5][u0]);
    float v0 = wy0.x * up0;
    v0 = fmaf(wy0.y, up1, v0);
    v0 = fmaf(wy0.z, up2, v0);
    v0 = fmaf(wy0.w, up3, v0);
    yrs[0][cc] = v0;
    if (nrow == 2) {
      float a, b2, c3, d;
      if (off1 == 1)      { a = up1; b2 = up2; c3 = up3; d = up4; }
      else if (off1 == 2) { a = up2; b2 = up3; c3 = up4; d = up5; }
      else                { a = up0; b2 = up1; c3 = up2; d = up3; }
      float v1 = wy1.x * a;
      v1 = fmaf(wy1.y, b2, v1);
      v1 = fmaf(wy1.z, c3, v1);
      v1 = fmaf(wy1.w, d, v1);
      yrs[1][cc] = v1;
    }
  }
  __syncthreads();
  const int* w2xS = P_I32(OFF_W2XS);
  size_t ob0 = ((size_t)kk * OH + oy0) * OW;
  size_t ob1 = ob0 + OW;
  for (int ox = tid; ox < OW; ox += 256) {
    int cb = w2xS[ox];
    float4 wx = *(const float4*)(P_F32(OFF_W2XW) + ox * 4);
    float a0 = wx.x * yrs[0][cb];
    a0 = fmaf(wx.y, yrs[0][cb + 1], a0);
    a0 = fmaf(wx.z, yrs[0][cb + 2], a0);
    a0 = fmaf(wx.w, yrs[0][cb + 3], a0);
    out[ob0 + ox] = (a0 > M_THR) ? 1.0f : 0.0f;
    if (nrow == 2) {
      float a1 = wx.x * yrs[1][cb];
      a1 = fmaf(wx.y, yrs[1][cb + 1], a1);
      a1 = fmaf(wx.z, yrs[1][cb + 2], a1);
      a1 = fmaf(wx.w, yrs[1][cb + 3], a1);
      out[ob1 + ox] = (a1 > M_THR) ? 1.0f : 0.0f;
    }
  }
}

extern "C" void kernel_launch(void* const* d_in, const int* in_sizes, int n_in,
                              void* d_out, int out_size, void* d_ws, size_t ws_size,
                              hipStream_t stream) {
  (void)in_sizes; (void)n_in; (void)out_size;
  const float* cate = (const float*)d_in[0];
  const float* segx = (const float*)d_in[1];
  const float* segy = (const float*)d_in[2];
  char* ws = (char*)d_ws;
  float* out = (float*)d_out;
  const bool bigws = (ws_size >= (size_t)WS_NEED);   // constant per-session -> capture-safe

  hipMemsetAsync(ws, 0, ZERO_BYTES, stream);

  {
    void* argsA[] = { (void*)&cate, (void*)&ws };
    hipLaunchCooperativeKernel((void*)kcoopA, dim3(152), dim3(512), argsA, 0, stream);
  }
  if (bigws) {
    hipLaunchKernelGGL(kmaskA, dim3(NWORDS), dim3(256), 0, stream, segx, segy, ws);
    void* argsB[] = { (void*)&ws, (void*)&out };
    hipLaunchCooperativeKernel((void*)kcoopB, dim3(NPRE + 120), dim3(512), argsB, 0, stream);
  } else {
    hipLaunchKernelGGL(kmask, dim3(NPRE), dim3(256), 0, stream, segx, segy, ws);
    hipLaunchKernelGGL(ksp, dim3(1), dim3(512), 0, stream, ws);
    hipLaunchKernelGGL(kpiou, dim3(2048), dim3(64), 0, stream, ws);
    hipLaunchKernelGGL(knms, dim3(1), dim3(512), 0, stream, ws, out);
  }
  hipLaunchKernelGGL(kout, dim3(MAXOUT * NRBLK), dim3(256), 0, stream, segx, segy, ws, out);
}

// Round 14
// 394.056 us; speedup vs baseline: 1.2134x; 1.2134x over previous
//
#include <hip/hip_runtime.h>
#include <stdint.h>

typedef unsigned int u32;
typedef unsigned long long u64;

#define NCELLS  3872
#define NCLS    80
#define NFLAT   309760
#define NPRE    500
#define NPAD    512
#define HH      200
#define WW      304
#define NPIX    60800
#define NWORDS  950      // 60800 / 64 exactly
#define MSTRIDE 960
#define MAXOUT  100
#define OH      427
#define OW      640
#define MH      800
#define MW      1216
#define MAXG    4096
#define MAXPAIRS 16384
#define OUT_LBL 27328000
#define OUT_SCR 27328100
#define ROWS_PER_BLK 2
#define NRBLK 214        // ceil(427/2); 100*214 = 21400 = 8*2675

#define S_THR 0.1f
#define M_THR 0.005f
#define U_THR 0.001f

// ---------------- workspace layout (bytes) ----------------
#define OFF_HIST1   0u        // 65536 u32 (value-bins: bin = (int)(v*65536))
#define OFF_META    263168u   // 16 u32: [2]cutBin [3]gatherCnt [4]pairCnt [5..8]done counters
#define ZERO_BYTES  263232u
#define OFF_CAND    263424u   // 4096 u64
#define OFF_RAW     296192u   // 512 f32
#define OFF_LABEL   300288u
#define OFF_XIND    302336u
#define OFF_YIND    304384u
#define OFF_STRIDE  306432u
#define OFF_SMF     308480u
#define OFF_SCORE   310528u
#define OFF_LABELK  312576u
#define OFF_ORDER   314624u
#define OFF_SSCORE  316672u
#define OFF_TOPC    318720u   // 128 i32
#define OFF_PAIRI   319232u   // 16384 u32
#define OFF_PAIRIOU 384768u   // 16384 f32
#define OFF_W1YT0   450304u   // 800 i32
#define OFF_W1YA    453504u   // 800 f32
#define OFF_W1YB    456704u
#define OFF_W1XT0   459904u   // 1216 i32
#define OFF_W1XA    464768u
#define OFF_W1XB    469632u
#define OFF_W2YS    474496u   // 427 i32
#define OFF_W2YW    476224u   // 427*4 f32 (16B aligned)
#define OFF_W2XS    483072u   // 640 i32
#define OFF_W2XW    485632u   // 640*4 f32 (16B aligned)
#define OFF_MASKS   495872u   // 500*960 u64 (candidate-major, for pair-IoU)
#define OFF_MASKT   4335872u  // 950*512 u64 (word-major, coalesced writes)
#define OFF_PARTD   8227072u  // 950*512 f64 word partial sums
#define WS_NEED     12118272u

#define P_U32(off) ((u32*)(ws + (off)))
#define P_I32(off) ((int*)(ws + (off)))
#define P_F32(off) ((float*)(ws + (off)))
#define P_U64(off) ((u64*)(ws + (off)))

__device__ __forceinline__ void levelMeta(int loc, int& td, int& sd, int& ng, float& st) {
  if (loc < 1600)      { td = 0;    sd = 0;   ng = 40; st = 4.f;  }
  else if (loc < 2896) { td = 1600; sd = 40;  ng = 36; st = 8.f;  }
  else if (loc < 3472) { td = 2896; sd = 76;  ng = 24; st = 16.f; }
  else if (loc < 3728) { td = 3472; sd = 100; ng = 16; st = 32.f; }
  else                 { td = 3728; sd = 116; ng = 12; st = 64.f; }
}

// value bin: exact & monotone for positive f32
__device__ __forceinline__ u32 vbin(float v) {
  int b = (int)(v * 65536.0f);
  if (b > 65535) b = 65535;
  if (b < 0) b = 0;
  return (u32)b;
}

__device__ __forceinline__ u64 shflx64(u64 v, int m) {
  u32 lo = (u32)v, hi = (u32)(v >> 32);
  lo = (u32)__shfl_xor((int)lo, m);
  hi = (u32)__shfl_xor((int)hi, m);
  return (((u64)hi) << 32) | lo;
}

// hybrid register/shuffle bitonic over 512 (block-local, 512 threads)
__device__ __forceinline__ u64 bitonic512(u64 key, int tid, u64* sk) {
  for (int k = 2; k <= NPAD; k <<= 1) {
    for (int j = k >> 1; j > 0; j >>= 1) {
      bool up = ((tid & k) == 0);
      u64 other;
      if (j < 64) {
        other = shflx64(key, j);
      } else {
        sk[tid] = key;
        __syncthreads();
        other = sk[tid ^ j];
        __syncthreads();
      }
      bool takeMax = (((tid & j) == 0) == up);
      key = takeMax ? (key > other ? key : other) : (key < other ? key : other);
    }
  }
  return key;
}

// last-block detector (threadFenceReduction pattern)
__device__ __forceinline__ bool lastBlock(u32* donePtr, int tid) {
  __shared__ int lastS;
  __threadfence();
  if (tid == 0) {
    u32 d = atomicAdd(donePtr, 1u);
    lastS = (d == gridDim.x - 1) ? 1 : 0;
  }
  __syncthreads();
  if (!lastS) return false;
  __threadfence();
  return true;
}

// candidate metadata + resize weight tables (512 threads)
__device__ void selwTail(char* ws, const u64* skSorted, int G, int tid) {
  {
    float rawv = -1.f; int lab = -1, xi = 0, yi = 0; float st = 3.0e38f;
    if (tid < NPRE && tid < G) {
      u64 key = skSorted[tid];
      u32 b = (u32)(key >> 32);
      u32 idx = ~((u32)(key & 0xffffffffu));
      rawv = __uint_as_float(b);
      int loc = (int)(idx / (u32)NCLS);
      lab = (int)(idx - (u32)loc * NCLS);
      int td, sd, ng; levelMeta(loc, td, sd, ng, st);
      int rel = loc - td;
      int row = rel / ng;
      yi = row + sd;
      xi = (rel - row * ng) + sd;
    }
    P_F32(OFF_RAW)[tid] = rawv;
    P_I32(OFF_LABEL)[tid] = lab;
    P_I32(OFF_XIND)[tid] = xi;
    P_I32(OFF_YIND)[tid] = yi;
    P_F32(OFF_STRIDE)[tid] = st;
    P_F32(OFF_SCORE)[tid] = 0.f;
    P_I32(OFF_LABELK)[tid] = -1;
    P_F32(OFF_SMF)[tid] = 0.f;
  }
  int t = tid;
  for (int r = t; r < MH; r += 512) {
    float s1 = ((float)r + 0.5f) * 0.25f - 0.5f;
    int t0 = (int)floorf(s1);
    float f = s1 - (float)t0;
    float wa = 1.f - f, wb = f;
    bool ia = (t0 >= 0) && (t0 < HH);
    bool ib = ((t0 + 1) >= 0) && ((t0 + 1) < HH);
    float tw = (ia ? wa : 0.f) + (ib ? wb : 0.f);
    float na = ia ? (wa / tw) : 0.f;
    float nb = ib ? (wb / tw) : 0.f;
    int base; float A, B;
    if (t0 < 0) { base = 0; A = nb; B = 0.f; }
    else if (t0 >= HH - 1) { base = HH - 2; A = 0.f; B = na; }
    else { base = t0; A = na; B = nb; }
    P_I32(OFF_W1YT0)[r] = base;
    P_F32(OFF_W1YA)[r] = A;
    P_F32(OFF_W1YB)[r] = B;
  }
  for (int c = t; c < MW; c += 512) {
    float s1 = ((float)c + 0.5f) * 0.25f - 0.5f;
    int t0 = (int)floorf(s1);
    float f = s1 - (float)t0;
    float wa = 1.f - f, wb = f;
    bool ia = (t0 >= 0) && (t0 < WW);
    bool ib = ((t0 + 1) >= 0) && ((t0 + 1) < WW);
    float tw = (ia ? wa : 0.f) + (ib ? wb : 0.f);
    float na = ia ? (wa / tw) : 0.f;
    float nb = ib ? (wb / tw) : 0.f;
    int base; float A, B;
    if (t0 < 0) { base = 0; A = nb; B = 0.f; }
    else if (t0 >= WW - 1) { base = WW - 2; A = 0.f; B = na; }
    else { base = t0; A = na; B = nb; }
    P_I32(OFF_W1XT0)[c] = base;
    P_F32(OFF_W1XA)[c] = A;
    P_F32(OFF_W1XB)[c] = B;
  }
  for (int o = t; o < OH; o += 512) {
    const float inv = (float)(800.0 / 427.0);
    float s2 = ((float)o + 0.5f) * inv - 0.5f;
    int rA = (int)ceilf(s2 - inv);
    int rB = (int)floorf(s2 + inv);
    if (rA < 0) rA = 0;
    if (rB > MH - 1) rB = MH - 1;
    float tot = 0.f;
    for (int r = rA; r <= rB; r++) {
      float x = fabsf(s2 - (float)r) / inv;
      float w = 1.f - x; if (w < 0.f) w = 0.f;
      tot += w;
    }
    int base = rA; if (base > MH - 4) base = MH - 4;
    float o4[4] = {0.f, 0.f, 0.f, 0.f};
    for (int r = rA; r <= rB; r++) {
      float x = fabsf(s2 - (float)r) / inv;
      float w = 1.f - x; if (w < 0.f) w = 0.f;
      o4[r - base] += w / tot;
    }
    P_I32(OFF_W2YS)[o] = base;
    float* wp = P_F32(OFF_W2YW) + o * 4;
    wp[0] = o4[0]; wp[1] = o4[1]; wp[2] = o4[2]; wp[3] = o4[3];
  }
  for (int o = t; o < OW; o += 512) {
    const float inv = (float)(1216.0 / 640.0);
    float s2 = ((float)o + 0.5f) * inv - 0.5f;
    int rA = (int)ceilf(s2 - inv);
    int rB = (int)floorf(s2 + inv);
    if (rA < 0) rA = 0;
    if (rB > MW - 1) rB = MW - 1;
    float tot = 0.f;
    for (int r = rA; r <= rB; r++) {
      float x = fabsf(s2 - (float)r) / inv;
      float w = 1.f - x; if (w < 0.f) w = 0.f;
      tot += w;
    }
    int base = rA; if (base > MW - 4) base = MW - 4;
    float o4[4] = {0.f, 0.f, 0.f, 0.f};
    for (int r = rA; r <= rB; r++) {
      float x = fabsf(s2 - (float)r) / inv;
      float w = 1.f - x; if (w < 0.f) w = 0.f;
      o4[r - base] += w / tot;
    }
    P_I32(OFF_W2XS)[o] = base;
    float* wp = P_F32(OFF_W2XW) + o * 4;
    wp[0] = o4[0]; wp[1] = o4[1]; wp[2] = o4[2]; wp[3] = o4[3];
  }
}

// -------- stage 1: histogram + (last block) cut-bin scan --------
__global__ void kh1c(const float* __restrict__ cate, char* __restrict__ ws) {
  int i = blockIdx.x * 256 + threadIdx.x;
  u32* h = P_U32(OFF_HIST1);
  if (i < NFLAT / 4) {
    float4 v = ((const float4*)cate)[i];
    if (v.x > S_THR) atomicAdd(&h[vbin(v.x)], 1u);
    if (v.y > S_THR) atomicAdd(&h[vbin(v.y)], 1u);
    if (v.z > S_THR) atomicAdd(&h[vbin(v.z)], 1u);
    if (v.w > S_THR) atomicAdd(&h[vbin(v.w)], 1u);
  }
  if (!lastBlock(&P_U32(OFF_META)[5], threadIdx.x)) return;
  // cut-bin scan (256 threads x 256 bins)
  __shared__ u32 sfx[256];
  __shared__ int cbS;
  __shared__ u32 aboveS;
  int t = threadIdx.x;
  u32 s = 0;
  for (int b = 0; b < 256; b++) s += h[t * 256 + b];
  sfx[t] = s;
  if (t == 0) cbS = -1;
  __syncthreads();
  for (int off = 1; off < 256; off <<= 1) {
    u32 v = (t + off < 256) ? sfx[t + off] : 0u;
    __syncthreads();
    sfx[t] += v;
    __syncthreads();
  }
  u32 nxt = (t < 255) ? sfx[t + 1] : 0u;
  if (sfx[t] >= NPRE && nxt < NPRE) { cbS = t; aboveS = nxt; }
  __syncthreads();
  u32* meta = P_U32(OFF_META);
  if (cbS < 0) { if (t == 0) meta[2] = 0u; return; }
  if (t == 0) {
    int cb = cbS;
    u32 cum = aboveS;
    u32 bin = (u32)(cb * 256);
    for (int b = 255; b >= 0; b--) {
      u32 hb = h[cb * 256 + b];
      if (cum + hb >= NPRE) { bin = (u32)(cb * 256 + b); break; }
      cum += hb;
    }
    meta[2] = bin;
  }
}

// -------- stage 1b: gather + (last block) bitonic top-500 + metadata + tables --------
__global__ __launch_bounds__(512) void kgs(const float* __restrict__ cate, char* __restrict__ ws) {
  __shared__ u64 sk[MAXG];
  int tid = threadIdx.x;
  int gtid = blockIdx.x * 512 + tid;
  int gstride = gridDim.x * 512;
  u32 key = P_U32(OFF_META)[2];
  u64* cand = P_U64(OFF_CAND);
  u32* cntp = &P_U32(OFF_META)[3];
  const float4* cate4 = (const float4*)cate;
  for (int i = gtid; i < NFLAT / 4; i += gstride) {
    float4 v = cate4[i];
    #pragma unroll
    for (int q = 0; q < 4; q++) {
      float f = (q == 0) ? v.x : (q == 1) ? v.y : (q == 2) ? v.z : v.w;
      if (f > S_THR && vbin(f) >= key) {
        u32 pos = atomicAdd(cntp, 1u);
        if (pos < MAXG) cand[pos] = (((u64)__float_as_uint(f)) << 32) | (u32)(~(u32)(i * 4 + q));
      }
    }
  }
  if (!lastBlock(&P_U32(OFF_META)[6], tid)) return;
  int G = (int)P_U32(OFF_META)[3]; if (G > MAXG) G = MAXG;
  int n = NPAD;
  while (n < G) n <<= 1;
  if (n == NPAD) {
    u64 k0 = (tid < G) ? cand[tid] : 0ull;
    k0 = bitonic512(k0, tid, sk);
    sk[tid] = k0;
    __syncthreads();
  } else {
    for (int i = tid; i < n; i += 512) sk[i] = (i < G) ? cand[i] : 0ull;
    __syncthreads();
    for (int k = 2; k <= n; k <<= 1) {
      for (int j = k >> 1; j > 0; j >>= 1) {
        for (int i = tid; i < n; i += 512) {
          int l = i ^ j;
          if (l > i) {
            u64 a = sk[i], b = sk[l];
            bool sw = ((i & k) == 0) ? (a < b) : (a > b);
            if (sw) { sk[i] = b; sk[l] = a; }
          }
        }
        __syncthreads();
      }
    }
  }
  selwTail(ws, sk, G, tid);
}

// -------- stage 2: word-major mask build, one candidate per THREAD --------
__global__ __launch_bounds__(256) void kmaskA(const float* __restrict__ segx, const float* __restrict__ segy,
                                              char* __restrict__ ws) {
  __shared__ float lx[128 * 64];
  __shared__ float ly[128 * 64];
  int w0 = blockIdx.x;
  int base = w0 << 6;
  int tid = threadIdx.x;
  for (int idx = tid; idx < 128 * 64; idx += 256) {
    int r = idx >> 6, col = idx & 63;
    int sw = col ^ (r & 63);              // XOR swizzle: distinct banks per row
    lx[(r << 6) + sw] = segx[(size_t)r * NPIX + base + col];
    ly[(r << 6) + sw] = segy[(size_t)r * NPIX + base + col];
  }
  __syncthreads();
  const int* xind = P_I32(OFF_XIND);
  const int* yind = P_I32(OFF_YIND);
  u64* maskT = P_U64(OFF_MASKT) + (size_t)w0 * NPAD;
  double* partD = (double*)(ws + OFF_PARTD) + (size_t)w0 * NPAD;
  for (int c = tid; c < NPRE; c += 256) {
    int xi = xind[c], yi = yind[c];
    const float* rx = &lx[xi << 6];
    const float* ry = &ly[yi << 6];
    int xk = xi & 63, yk = yi & 63;
    u32 lo = 0, hi = 0;
    double sum = 0.0;
    #pragma unroll 8
    for (int p = 0; p < 32; p++) {
      float s = rx[p ^ xk] * ry[p ^ yk];
      if (s > M_THR) { lo |= (1u << p); sum += (double)s; }
    }
    #pragma unroll 8
    for (int p = 32; p < 64; p++) {
      float s = rx[p ^ xk] * ry[p ^ yk];
      if (s > M_THR) { hi |= (1u << (p - 32)); sum += (double)s; }
    }
    maskT[c] = (((u64)hi) << 32) | lo;
    partD[c] = sum;
  }
}

// -------- stage 3: BT reduction/transpose + (last block) sort + pair list --------
__global__ __launch_bounds__(512) void kmaskBTs(char* __restrict__ ws) {
  __shared__ u64 tile[64][65];
  __shared__ double cd[512];
  __shared__ int ci[512];
  __shared__ u64 sk[NPAD];
  __shared__ short slab[NPAD];
  __shared__ u32 scan[NPAD];
  int bid = blockIdx.x;
  int tid = threadIdx.x;
  const u64* maskT = P_U64(OFF_MASKT);
  if (bid < NPRE) {
    int c = bid;
    const double* partD = (const double*)(ws + OFF_PARTD);
    double ds = 0.0; int cnt = 0;
    for (int w = tid; w < NWORDS; w += 512) {
      ds += partD[(size_t)w * NPAD + c];
      cnt += (int)__popcll(maskT[(size_t)w * NPAD + c]);
    }
    cd[tid] = ds; ci[tid] = cnt;
    __syncthreads();
    for (int s2 = 256; s2 > 0; s2 >>= 1) {
      if (tid < s2) { ci[tid] += ci[tid + s2]; cd[tid] += cd[tid + s2]; }
      __syncthreads();
    }
    if (tid == 0) {
      float sm = (float)ci[0];
      float rawv = P_F32(OFF_RAW)[c];
      bool valid = rawv > S_THR;
      bool keep = valid && (sm > P_F32(OFF_STRIDE)[c]);
      float ssf = (float)cd[0];
      float segsc = ssf / fmaxf(sm, 1e-6f);
      P_F32(OFF_SCORE)[c] = keep ? (rawv * segsc) : 0.f;
      P_F32(OFF_SMF)[c] = keep ? sm : 0.f;
      P_I32(OFF_LABELK)[c] = keep ? P_I32(OFF_LABEL)[c] : -1;
    }
  } else {
    int q = bid - NPRE;                 // 0..119 = 15 x 8 tiles
    int w0 = (q % 15) << 6;
    int c0 = (q / 15) << 6;
    for (int idx = tid; idx < 64 * 64; idx += 512) {
      int rw = idx >> 6, cc = idx & 63;
      int w = w0 + rw;
      tile[rw][cc] = (w < NWORDS) ? maskT[(size_t)w * NPAD + (c0 + cc)] : 0ull;
    }
    __syncthreads();
    u64* masks = P_U64(OFF_MASKS);
    for (int idx = tid; idx < 64 * 64; idx += 512) {
      int rc = idx >> 6, wwi = idx & 63;
      int c = c0 + rc, w = w0 + wwi;
      if (c < NPRE && w < NWORDS) masks[(size_t)c * MSTRIDE + w] = tile[wwi][rc];
    }
  }
  if (!lastBlock(&P_U32(OFF_META)[7], tid)) return;
  // tail: descending sort + same-class pair list (512 threads)
  float sc = (tid < NPRE) ? P_F32(OFF_SCORE)[tid] : 0.f;
  u64 key = (((u64)__float_as_uint(sc)) << 32) | (u32)(NPAD - 1 - tid);
  key = bitonic512(key, tid, sk);
  int ord = NPAD - 1 - (int)(key & 0xffffffffu);
  P_I32(OFF_ORDER)[tid] = ord;
  P_F32(OFF_SSCORE)[tid] = __uint_as_float((u32)(key >> 32));
  const int* labelK = P_I32(OFF_LABELK);
  int lab = (tid < NPRE) ? labelK[ord] : -1;
  slab[tid] = (short)lab;
  __syncthreads();
  u32 cnt = 0;
  if (lab >= 0) {
    short lj = (short)lab;
    for (int i = 0; i < tid; i++) if (slab[i] == lj) cnt++;
  }
  scan[tid] = cnt;
  __syncthreads();
  for (int off = 1; off < NPAD; off <<= 1) {
    u32 v = (tid >= off) ? scan[tid - off] : 0u;
    __syncthreads();
    scan[tid] += v;
    __syncthreads();
  }
  if (tid == NPAD - 1) {
    u32 tot = scan[tid];
    P_U32(OFF_META)[4] = (tot > MAXPAIRS) ? MAXPAIRS : tot;
  }
  if (lab >= 0 && cnt) {
    u32 pos = scan[tid] - cnt;
    short lj = (short)lab;
    u32* pairI = P_U32(OFF_PAIRI);
    for (int i = 0; i < tid; i++) {
      if (slab[i] == lj) {
        if (pos < MAXPAIRS) pairI[pos] = (((u32)i) << 16) | (u32)tid;
        pos++;
      }
    }
  }
}

// -------- stage 4: pair IoU (8 waves/block) + (last block) matrix-NMS + top-100 --------
__global__ __launch_bounds__(512) void kpiouN(char* __restrict__ ws, float* __restrict__ out) {
  __shared__ int compI[NPAD];
  __shared__ int coefI[NPAD];
  __shared__ u64 sk[NPAD];
  int bid = blockIdx.x;
  int tid = threadIdx.x;
  {
    int P = (int)P_U32(OFF_META)[4]; if (P > MAXPAIRS) P = MAXPAIRS;
    const int* order = P_I32(OFF_ORDER);
    const float* smf = P_F32(OFF_SMF);
    const u64* masks = P_U64(OFF_MASKS);
    int wid = tid >> 6, lane = tid & 63;
    int gw = bid * 8 + wid;
    int gwstride = gridDim.x * 8;
    for (int p = gw; p < P; p += gwstride) {
      u32 ij = P_U32(OFF_PAIRI)[p];
      int oi = order[ij >> 16];
      int oj = order[ij & 0xffffu];
      const u64* mi = masks + (size_t)oi * MSTRIDE;
      const u64* mj = masks + (size_t)oj * MSTRIDE;
      int inter = 0;
      for (int w = lane; w < NWORDS; w += 64)
        inter += (int)__popcll(mi[w] & mj[w]);
      for (int off = 32; off > 0; off >>= 1)
        inter += __shfl_down(inter, off);
      if (lane == 0) {
        float fi = (float)inter;
        float uni = (smf[oj] + smf[oi]) - fi;
        float iou = (uni > 0.f) ? (fi / fmaxf(uni, 1e-12f)) : 0.f;
        P_F32(OFF_PAIRIOU)[p] = iou;
      }
    }
  }
  if (!lastBlock(&P_U32(OFF_META)[8], tid)) return;
  // tail: matrix-NMS decay + top-100 (512 threads)
  int P = (int)P_U32(OFF_META)[4]; if (P > MAXPAIRS) P = MAXPAIRS;
  const u32* pairI = P_U32(OFF_PAIRI);
  const float* pairIou = P_F32(OFF_PAIRIOU);
  const float* sscore = P_F32(OFF_SSCORE);
  const int* order = P_I32(OFF_ORDER);
  const int* labelK = P_I32(OFF_LABELK);
  int* topc = P_I32(OFF_TOPC);
  compI[tid] = 0;
  coefI[tid] = __float_as_int(1.0f);
  __syncthreads();
  for (int p = tid; p < P; p += 512) {
    int j = (int)(pairI[p] & 0xffffu);
    atomicMax(&compI[j], __float_as_int(pairIou[p]));
  }
  __syncthreads();
  for (int p = tid; p < P; p += 512) {
    u32 ij = pairI[p];
    int i = (int)(ij >> 16), j = (int)(ij & 0xffffu);
    float x = pairIou[p];
    float c = __int_as_float(compI[i]);
    float x2 = x * x, c2 = c * c;
    float r = (float)exp(-2.0 * ((double)x2 - (double)c2));
    atomicMin(&coefI[j], __float_as_int(r));
  }
  __syncthreads();
  float ns = 0.f;
  if (tid < NPRE) {
    ns = sscore[tid] * __int_as_float(coefI[tid]);
    ns = (ns > U_THR) ? ns : 0.f;
  }
  u64 key = (((u64)__float_as_uint(ns)) << 32) | (u32)(NPAD - 1 - tid);
  key = bitonic512(key, tid, sk);
  if (tid < MAXOUT) {
    int pos = NPAD - 1 - (int)(key & 0xffffffffu);
    int cand = order[pos];
    topc[tid] = cand;
    out[OUT_LBL + tid] = (float)labelK[cand];
    out[OUT_SCR + tid] = __uint_as_float((u32)(key >> 32));
  }
}

// -------- fallback (small ws): candidate-major mask + standalone chain --------
__global__ __launch_bounds__(256) void kmask(const float* __restrict__ segx, const float* __restrict__ segy,
                                             char* __restrict__ ws) {
  int c = blockIdx.x;
  int tid = threadIdx.x;
  int lane = tid & 63, wv = tid >> 6;
  const float* X = segx + (size_t)P_I32(OFF_XIND)[c] * NPIX;
  const float* Y = segy + (size_t)P_I32(OFF_YIND)[c] * NPIX;
  u64* mrow = P_U64(OFF_MASKS) + (size_t)c * MSTRIDE;
  int cnt = 0;
  double ssum = 0.0;
  for (int w0 = wv; w0 < NWORDS; w0 += 4) {
    int p = (w0 << 6) + lane;
    float s = X[p] * Y[p];
    bool b = s > M_THR;
    u64 bal = __ballot(b ? 1 : 0);
    if (lane == 0) mrow[w0] = bal;
    if (b) { cnt++; ssum += (double)s; }
  }
  __shared__ int ci[256];
  __shared__ double cd[256];
  ci[tid] = cnt; cd[tid] = ssum;
  __syncthreads();
  for (int s2 = 128; s2 > 0; s2 >>= 1) {
    if (tid < s2) { ci[tid] += ci[tid + s2]; cd[tid] += cd[tid + s2]; }
    __syncthreads();
  }
  if (tid == 0) {
    float sm = (float)ci[0];
    float rawv = P_F32(OFF_RAW)[c];
    bool valid = rawv > S_THR;
    bool keep = valid && (sm > P_F32(OFF_STRIDE)[c]);
    float ssf = (float)cd[0];
    float segsc = ssf / fmaxf(sm, 1e-6f);
    P_F32(OFF_SCORE)[c] = keep ? (rawv * segsc) : 0.f;
    P_F32(OFF_SMF)[c] = keep ? sm : 0.f;
    P_I32(OFF_LABELK)[c] = keep ? P_I32(OFF_LABEL)[c] : -1;
  }
}

__global__ __launch_bounds__(512) void ksp(char* __restrict__ ws) {
  __shared__ u64 sk[NPAD];
  __shared__ short slab[NPAD];
  __shared__ u32 scan[NPAD];
  int t = threadIdx.x;
  float sc = (t < NPRE) ? P_F32(OFF_SCORE)[t] : 0.f;
  u64 key = (((u64)__float_as_uint(sc)) << 32) | (u32)(NPAD - 1 - t);
  key = bitonic512(key, t, sk);
  int ord = NPAD - 1 - (int)(key & 0xffffffffu);
  P_I32(OFF_ORDER)[t] = ord;
  P_F32(OFF_SSCORE)[t] = __uint_as_float((u32)(key >> 32));
  const int* labelK = P_I32(OFF_LABELK);
  int lab = (t < NPRE) ? labelK[ord] : -1;
  slab[t] = (short)lab;
  __syncthreads();
  u32 cnt = 0;
  if (lab >= 0) {
    short lj = (short)lab;
    for (int i = 0; i < t; i++) if (slab[i] == lj) cnt++;
  }
  scan[t] = cnt;
  __syncthreads();
  for (int off = 1; off < NPAD; off <<= 1) {
    u32 v = (t >= off) ? scan[t - off] : 0u;
    __syncthreads();
    scan[t] += v;
    __syncthreads();
  }
  if (t == NPAD - 1) {
    u32 tot = scan[t];
    P_U32(OFF_META)[4] = (tot > MAXPAIRS) ? MAXPAIRS : tot;
  }
  if (lab >= 0 && cnt) {
    u32 pos = scan[t] - cnt;
    short lj = (short)lab;
    u32* pairI = P_U32(OFF_PAIRI);
    for (int i = 0; i < t; i++) {
      if (slab[i] == lj) {
        if (pos < MAXPAIRS) pairI[pos] = (((u32)i) << 16) | (u32)t;
        pos++;
      }
    }
  }
}

__global__ __launch_bounds__(64) void kpiou(char* __restrict__ ws) {
  int P = (int)P_U32(OFF_META)[4]; if (P > MAXPAIRS) P = MAXPAIRS;
  const int* order = P_I32(OFF_ORDER);
  const float* smf = P_F32(OFF_SMF);
  const u64* masks = P_U64(OFF_MASKS);
  for (int p = blockIdx.x; p < P; p += gridDim.x) {
    u32 ij = P_U32(OFF_PAIRI)[p];
    int oi = order[ij >> 16];
    int oj = order[ij & 0xffffu];
    const u64* mi = masks + (size_t)oi * MSTRIDE;
    const u64* mj = masks + (size_t)oj * MSTRIDE;
    int inter = 0;
    for (int w = threadIdx.x; w < NWORDS; w += 64)
      inter += (int)__popcll(mi[w] & mj[w]);
    for (int off = 32; off > 0; off >>= 1)
      inter += __shfl_down(inter, off);
    if (threadIdx.x == 0) {
      float fi = (float)inter;
      float uni = (smf[oj] + smf[oi]) - fi;
      float iou = (uni > 0.f) ? (fi / fmaxf(uni, 1e-12f)) : 0.f;
      P_F32(OFF_PAIRIOU)[p] = iou;
    }
  }
}

__global__ __launch_bounds__(512) void knms(char* __restrict__ ws, float* __restrict__ out) {
  __shared__ int compI[NPAD];
  __shared__ int coefI[NPAD];
  __shared__ u64 sk[NPAD];
  int t = threadIdx.x;
  int P = (int)P_U32(OFF_META)[4]; if (P > MAXPAIRS) P = MAXPAIRS;
  const u32* pairI = P_U32(OFF_PAIRI);
  const float* pairIou = P_F32(OFF_PAIRIOU);
  const float* sscore = P_F32(OFF_SSCORE);
  const int* order = P_I32(OFF_ORDER);
  const int* labelK = P_I32(OFF_LABELK);
  int* topc = P_I32(OFF_TOPC);
  compI[t] = 0;
  coefI[t] = __float_as_int(1.0f);
  __syncthreads();
  for (int p = t; p < P; p += 512) {
    int j = (int)(pairI[p] & 0xffffu);
    atomicMax(&compI[j], __float_as_int(pairIou[p]));
  }
  __syncthreads();
  for (int p = t; p < P; p += 512) {
    u32 ij = pairI[p];
    int i = (int)(ij >> 16), j = (int)(ij & 0xffffu);
    float x = pairIou[p];
    float c = __int_as_float(compI[i]);
    float x2 = x * x, c2 = c * c;
    float r = (float)exp(-2.0 * ((double)x2 - (double)c2));
    atomicMin(&coefI[j], __float_as_int(r));
  }
  __syncthreads();
  float ns = 0.f;
  if (t < NPRE) {
    ns = sscore[t] * __int_as_float(coefI[t]);
    ns = (ns > U_THR) ? ns : 0.f;
  }
  u64 key = (((u64)__float_as_uint(ns)) << 32) | (u32)(NPAD - 1 - t);
  key = bitonic512(key, t, sk);
  if (t < MAXOUT) {
    int pos = NPAD - 1 - (int)(key & 0xffffffffu);
    int cand = order[pos];
    topc[t] = cand;
    out[OUT_LBL + t] = (float)labelK[cand];
    out[OUT_SCR + t] = __uint_as_float((u32)(key >> 32));
  }
}

// -------- stage 7: fused double-resize + binarize; register stage-1 --------
__global__ __launch_bounds__(256) void kout(const float* __restrict__ segx, const float* __restrict__ segy,
                                            char* __restrict__ ws, float* __restrict__ out) {
  __shared__ float t1s[6][WW];   // y-interp mid rows
  __shared__ float yrs[2][MW];   // per-out-row y-contracted mid columns
  int flat = blockIdx.x;
  int w = (flat & 7) * 2675 + (flat >> 3);   // bijective XCD swizzle (21400 = 8*2675)
  int kk = w / NRBLK;
  int r2 = w - kk * NRBLK;
  int oy0 = r2 * ROWS_PER_BLK;
  int nrow = (oy0 + 1 < OH) ? 2 : 1;
  int tid = threadIdx.x;
  int cand = P_I32(OFF_TOPC)[kk];
  const float* X = segx + (size_t)P_I32(OFF_XIND)[cand] * NPIX;
  const float* Y = segy + (size_t)P_I32(OFF_YIND)[cand] * NPIX;
  const int* w2ys = P_I32(OFF_W2YS);
  int rb = w2ys[oy0];
  const int* w1yT0 = P_I32(OFF_W1YT0);
  const float* w1yA = P_F32(OFF_W1YA);
  const float* w1yB = P_F32(OFF_W1YB);
  int smin = w1yT0[rb];
  float Ay[6], By[6]; int i0a[6];
  #pragma unroll
  for (int mr = 0; mr < 6; mr++) {
    int r = rb + mr; if (r > MH - 1) r = MH - 1;
    i0a[mr] = w1yT0[r] - smin;
    Ay[mr] = w1yA[r];
    By[mr] = w1yB[r];
  }
  {
    int r0 = smin;     if (r0 > HH - 1) r0 = HH - 1;
    int r1 = smin + 1; if (r1 > HH - 1) r1 = HH - 1;
    int r2s = smin + 2; if (r2s > HH - 1) r2s = HH - 1;
    int r3 = smin + 3; if (r3 > HH - 1) r3 = HH - 1;
    const float* X0 = X + r0 * WW; const float* Y0 = Y + r0 * WW;
    const float* X1 = X + r1 * WW; const float* Y1 = Y + r1 * WW;
    const float* X2 = X + r2s * WW; const float* Y2 = Y + r2s * WW;
    const float* X3 = X + r3 * WW; const float* Y3 = Y + r3 * WW;
    for (int u = tid; u < WW; u += 256) {
      float s0 = X0[u] * Y0[u];
      float s1 = X1[u] * Y1[u];
      float s2 = X2[u] * Y2[u];
      float s3 = X3[u] * Y3[u];
      #pragma unroll
      for (int mr = 0; mr < 6; mr++) {
        int i0 = i0a[mr];
        float sa, sb;
        if (i0 == 0)      { sa = s0; sb = s1; }
        else if (i0 == 1) { sa = s1; sb = s2; }
        else              { sa = s2; sb = s3; }
        t1s[mr][u] = fmaf(By[mr], sb, Ay[mr] * sa);
      }
    }
  }
  __syncthreads();
  const int* w1xT0 = P_I32(OFF_W1XT0);
  const float* w1xA = P_F32(OFF_W1XA);
  const float* w1xB = P_F32(OFF_W1XB);
  float4 wy0 = *(const float4*)(P_F32(OFF_W2YW) + oy0 * 4);
  int oy1 = (nrow == 2) ? (oy0 + 1) : oy0;
  float4 wy1 = *(const float4*)(P_F32(OFF_W2YW) + oy1 * 4);
  int off1 = w2ys[oy1] - rb;
  for (int cc = tid; cc < MW; cc += 256) {
    int u0 = w1xT0[cc];
    float xa = w1xA[cc], xb = w1xB[cc];
    float up0 = fmaf(xb, t1s[0][u0 + 1], xa * t1s[0][u0]);
    float up1 = fmaf(xb, t1s[1][u0 + 1], xa * t1s[1][u0]);
    float up2 = fmaf(xb, t1s[2][u0 + 1], xa * t1s[2][u0]);
    float up3 = fmaf(xb, t1s[3][u0 + 1], xa * t1s[3][u0]);
    float up4 = fmaf(xb, t1s[4][u0 + 1], xa * t1s[4][u0]);
    float up5 = fmaf(xb, t1s[5][u0 + 1], xa * t1s[5][u0]);
    float v0 = wy0.x * up0;
    v0 = fmaf(wy0.y, up1, v0);
    v0 = fmaf(wy0.z, up2, v0);
    v0 = fmaf(wy0.w, up3, v0);
    yrs[0][cc] = v0;
    if (nrow == 2) {
      float a, b2, c3, d;
      if (off1 == 1)      { a = up1; b2 = up2; c3 = up3; d = up4; }
      else if (off1 == 2) { a = up2; b2 = up3; c3 = up4; d = up5; }
      else                { a = up0; b2 = up1; c3 = up2; d = up3; }
      float v1 = wy1.x * a;
      v1 = fmaf(wy1.y, b2, v1);
      v1 = fmaf(wy1.z, c3, v1);
      v1 = fmaf(wy1.w, d, v1);
      yrs[1][cc] = v1;
    }
  }
  __syncthreads();
  const int* w2xS = P_I32(OFF_W2XS);
  size_t ob0 = ((size_t)kk * OH + oy0) * OW;
  size_t ob1 = ob0 + OW;
  for (int ox = tid; ox < OW; ox += 256) {
    int cb = w2xS[ox];
    float4 wx = *(const float4*)(P_F32(OFF_W2XW) + ox * 4);
    float a0 = wx.x * yrs[0][cb];
    a0 = fmaf(wx.y, yrs[0][cb + 1], a0);
    a0 = fmaf(wx.z, yrs[0][cb + 2], a0);
    a0 = fmaf(wx.w, yrs[0][cb + 3], a0);
    out[ob0 + ox] = (a0 > M_THR) ? 1.0f : 0.0f;
    if (nrow == 2) {
      float a1 = wx.x * yrs[1][cb];
      a1 = fmaf(wx.y, yrs[1][cb + 1], a1);
      a1 = fmaf(wx.z, yrs[1][cb + 2], a1);
      a1 = fmaf(wx.w, yrs[1][cb + 3], a1);
      out[ob1 + ox] = (a1 > M_THR) ? 1.0f : 0.0f;
    }
  }
}

extern "C" void kernel_launch(void* const* d_in, const int* in_sizes, int n_in,
                              void* d_out, int out_size, void* d_ws, size_t ws_size,
                              hipStream_t stream) {
  (void)in_sizes; (void)n_in; (void)out_size;
  const float* cate = (const float*)d_in[0];
  const float* segx = (const float*)d_in[1];
  const float* segy = (const float*)d_in[2];
  char* ws = (char*)d_ws;
  float* out = (float*)d_out;
  const bool bigws = (ws_size >= (size_t)WS_NEED);   // constant per-session -> capture-safe

  hipMemsetAsync(ws, 0, ZERO_BYTES, stream);

  hipLaunchKernelGGL(kh1c, dim3((NFLAT / 4 + 255) / 256), dim3(256), 0, stream, cate, ws);
  hipLaunchKernelGGL(kgs, dim3((NFLAT / 4 + 511) / 512), dim3(512), 0, stream, cate, ws);
  if (bigws) {
    hipLaunchKernelGGL(kmaskA, dim3(NWORDS), dim3(256), 0, stream, segx, segy, ws);
    hipLaunchKernelGGL(kmaskBTs, dim3(NPRE + 120), dim3(512), 0, stream, ws);
    hipLaunchKernelGGL(kpiouN, dim3(256), dim3(512), 0, stream, ws, out);
  } else {
    hipLaunchKernelGGL(kmask, dim3(NPRE), dim3(256), 0, stream, segx, segy, ws);
    hipLaunchKernelGGL(ksp, dim3(1), dim3(512), 0, stream, ws);
    hipLaunchKernelGGL(kpiou, dim3(2048), dim3(64), 0, stream, ws);
    hipLaunchKernelGGL(knms, dim3(1), dim3(512), 0, stream, ws, out);
  }
  hipLaunchKernelGGL(kout, dim3(MAXOUT * NRBLK), dim3(256), 0, stream, segx, segy, ws, out);
}

// Round 15
// 232.639 us; speedup vs baseline: 2.0554x; 1.6939x over previous
//
#include <hip/hip_runtime.h>
#include <stdint.h>

typedef unsigned int u32;
typedef unsigned long long u64;

#define NCELLS  3872
#define NCLS    80
#define NFLAT   309760
#define NPRE    500
#define NPAD    512
#define HH      200
#define WW      304
#define NPIX    60800
#define NWORDS  950      // 60800 / 64 exactly
#define MSTRIDE 960
#define MAXOUT  100
#define OH      427
#define OW      640
#define MH      800
#define MW      1216
#define MAXG    4096
#define MAXPAIRS 16384
#define OUT_LBL 27328000
#define OUT_SCR 27328100
#define ROWS_PER_BLK 2
#define NRBLK 214        // ceil(427/2); 100*214 = 21400 = 8*2675

#define S_THR 0.1f
#define M_THR 0.005f
#define U_THR 0.001f

// ---------------- workspace layout (bytes) ----------------
#define OFF_HIST1   0u        // 65536 u32 (value-bins: bin = (int)(v*65536))
#define OFF_META    263168u   // 16 u32: [0]cutbin [1]cntAbove [2]cutBin [3]gatherCnt [4]pairCnt
#define ZERO_BYTES  263232u
#define OFF_CAND    263424u   // 4096 u64
#define OFF_RAW     296192u   // 512 f32
#define OFF_LABEL   300288u
#define OFF_XIND    302336u
#define OFF_YIND    304384u
#define OFF_STRIDE  306432u
#define OFF_SMF     308480u
#define OFF_SCORE   310528u
#define OFF_LABELK  312576u
#define OFF_ORDER   314624u
#define OFF_SSCORE  316672u
#define OFF_TOPC    318720u   // 128 i32
#define OFF_PAIRI   319232u   // 16384 u32
#define OFF_PAIRIOU 384768u   // 16384 f32
#define OFF_W1YT0   450304u   // 800 i32
#define OFF_W1YA    453504u   // 800 f32
#define OFF_W1YB    456704u
#define OFF_W1XT0   459904u   // 1216 i32
#define OFF_W1XA    464768u
#define OFF_W1XB    469632u
#define OFF_W2YS    474496u   // 427 i32
#define OFF_W2YW    476224u   // 427*4 f32 (16B aligned)
#define OFF_W2XS    483072u   // 640 i32
#define OFF_W2XW    485632u   // 640*4 f32 (16B aligned)
#define OFF_MASKS   495872u   // 500*960 u64 (candidate-major, for kpiou)
#define OFF_MASKT   4335872u  // 950*512 u64 (word-major, coalesced writes)
#define OFF_PARTD   8227072u  // 950*512 f64 word partial sums
#define WS_NEED     12118272u

#define P_U32(off) ((u32*)(ws + (off)))
#define P_I32(off) ((int*)(ws + (off)))
#define P_F32(off) ((float*)(ws + (off)))
#define P_U64(off) ((u64*)(ws + (off)))

__device__ __forceinline__ void levelMeta(int loc, int& td, int& sd, int& ng, float& st) {
  if (loc < 1600)      { td = 0;    sd = 0;   ng = 40; st = 4.f;  }
  else if (loc < 2896) { td = 1600; sd = 40;  ng = 36; st = 8.f;  }
  else if (loc < 3472) { td = 2896; sd = 76;  ng = 24; st = 16.f; }
  else if (loc < 3728) { td = 3472; sd = 100; ng = 16; st = 32.f; }
  else                 { td = 3728; sd = 116; ng = 12; st = 64.f; }
}

// value bin: exact & monotone for positive f32
__device__ __forceinline__ u32 vbin(float v) {
  int b = (int)(v * 65536.0f);
  if (b > 65535) b = 65535;
  if (b < 0) b = 0;
  return (u32)b;
}

__device__ __forceinline__ u64 shflx64(u64 v, int m) {
  u32 lo = (u32)v, hi = (u32)(v >> 32);
  lo = (u32)__shfl_xor((int)lo, m);
  hi = (u32)__shfl_xor((int)hi, m);
  return (((u64)hi) << 32) | lo;
}

// -------- stage 1: value-bin histogram (float4 loads) --------
__global__ void kh1(const float* __restrict__ cate, char* __restrict__ ws) {
  int i = blockIdx.x * 256 + threadIdx.x;
  if (i >= NFLAT / 4) return;
  float4 v = ((const float4*)cate)[i];
  u32* h = P_U32(OFF_HIST1);
  if (v.x > S_THR) atomicAdd(&h[vbin(v.x)], 1u);
  if (v.y > S_THR) atomicAdd(&h[vbin(v.y)], 1u);
  if (v.z > S_THR) atomicAdd(&h[vbin(v.z)], 1u);
  if (v.w > S_THR) atomicAdd(&h[vbin(v.w)], 1u);
}

// parallel suffix-scan to find the value-bin containing the 500th value
__global__ __launch_bounds__(1024) void kc1(char* __restrict__ ws) {
  __shared__ u32 cs[1024];
  __shared__ u32 sfx[1024];
  __shared__ int cbS;
  __shared__ u32 aboveS;
  int t = threadIdx.x;
  const u32* h = P_U32(OFF_HIST1);
  u32 s = 0;
  for (int b = 0; b < 64; b++) s += h[t * 64 + b];
  cs[t] = s; sfx[t] = s;
  if (t == 0) cbS = -1;
  __syncthreads();
  for (int off = 1; off < 1024; off <<= 1) {
    u32 v = (t + off < 1024) ? sfx[t + off] : 0u;
    __syncthreads();
    sfx[t] += v;
    __syncthreads();
  }
  u32 nxt = (t < 1023) ? sfx[t + 1] : 0u;
  if (sfx[t] >= NPRE && nxt < NPRE) { cbS = t; aboveS = nxt; }
  __syncthreads();
  u32* meta = P_U32(OFF_META);
  if (cbS < 0) {
    if (t == 0) { meta[0] = 0u; meta[1] = sfx[0]; meta[2] = 0u; }
    return;
  }
  int cb = cbS;
  if (t < 64) cs[t] = h[cb * 64 + t];
  __syncthreads();
  if (t == 0) {
    u32 cum = aboveS;
    u32 bin = (u32)(cb * 64);
    for (int b = 63; b >= 0; b--) {
      u32 hb = cs[b];
      if (cum + hb >= NPRE) { bin = (u32)(cb * 64 + b); break; }
      cum += hb;
    }
    meta[0] = bin; meta[1] = cum; meta[2] = bin;
  }
}

__global__ void kg(const float* __restrict__ cate, char* __restrict__ ws) {
  u32 key = P_U32(OFF_META)[2];
  int i = blockIdx.x * 256 + threadIdx.x;
  if (i >= NFLAT / 4) return;
  float4 v = ((const float4*)cate)[i];
  u64* cand = P_U64(OFF_CAND);
  u32* cntp = &P_U32(OFF_META)[3];
  #pragma unroll
  for (int q = 0; q < 4; q++) {
    float f = (q == 0) ? v.x : (q == 1) ? v.y : (q == 2) ? v.z : v.w;
    if (f > S_THR && vbin(f) >= key) {
      u32 pos = atomicAdd(cntp, 1u);
      if (pos < MAXG) cand[pos] = (((u64)__float_as_uint(f)) << 32) | (u32)(~(u32)(i * 4 + q));
    }
  }
}

// bitonic top-500 (hybrid shuffle fast path when G<=512) + metadata + weight tables
__global__ __launch_bounds__(1024) void kselw(char* __restrict__ ws) {
  __shared__ u64 sk[MAXG];
  int tid = threadIdx.x;
  int G = (int)P_U32(OFF_META)[3]; if (G > MAXG) G = MAXG;
  int n = NPAD;
  while (n < G) n <<= 1;
  const u64* cand = P_U64(OFF_CAND);
  if (n == NPAD) {
    u64 key = (tid < NPAD) ? ((tid < G) ? cand[tid] : 0ull) : 0ull;
    for (int k = 2; k <= NPAD; k <<= 1) {
      for (int j = k >> 1; j > 0; j >>= 1) {
        bool up = ((tid & k) == 0);
        u64 other;
        if (j < 64) {
          other = shflx64(key, j);
        } else {
          if (tid < NPAD) sk[tid] = key;
          __syncthreads();
          other = sk[(tid ^ j) & (NPAD - 1)];
          __syncthreads();
        }
        bool takeMax = (((tid & j) == 0) == up);
        u64 nk = takeMax ? (key > other ? key : other) : (key < other ? key : other);
        if (tid < NPAD) key = nk;
      }
    }
    if (tid < NPAD) sk[tid] = key;
    __syncthreads();
  } else {
    for (int i = tid; i < n; i += 1024) sk[i] = (i < G) ? cand[i] : 0ull;
    __syncthreads();
    for (int k = 2; k <= n; k <<= 1) {
      for (int j = k >> 1; j > 0; j >>= 1) {
        for (int i = tid; i < n; i += 1024) {
          int l = i ^ j;
          if (l > i) {
            u64 a = sk[i], b = sk[l];
            bool sw = ((i & k) == 0) ? (a < b) : (a > b);
            if (sw) { sk[i] = b; sk[l] = a; }
          }
        }
        __syncthreads();
      }
    }
  }
  if (tid < NPAD) {
    float rawv = -1.f; int lab = -1, xi = 0, yi = 0; float st = 3.0e38f;
    if (tid < NPRE && tid < G) {
      u64 key = sk[tid];
      u32 b = (u32)(key >> 32);
      u32 idx = ~((u32)(key & 0xffffffffu));
      rawv = __uint_as_float(b);
      int loc = (int)(idx / (u32)NCLS);
      lab = (int)(idx - (u32)loc * NCLS);
      int td, sd, ng; levelMeta(loc, td, sd, ng, st);
      int rel = loc - td;
      int row = rel / ng;
      yi = row + sd;
      xi = (rel - row * ng) + sd;
    }
    P_F32(OFF_RAW)[tid] = rawv;
    P_I32(OFF_LABEL)[tid] = lab;
    P_I32(OFF_XIND)[tid] = xi;
    P_I32(OFF_YIND)[tid] = yi;
    P_F32(OFF_STRIDE)[tid] = st;
    P_F32(OFF_SCORE)[tid] = 0.f;
    P_I32(OFF_LABELK)[tid] = -1;
    P_F32(OFF_SMF)[tid] = 0.f;
  }
  // ---- fused: resize weight tables (mimic jax.image.resize f32 math) ----
  int t = tid;
  for (int r = t; r < MH; r += 1024) {
    float s1 = ((float)r + 0.5f) * 0.25f - 0.5f;
    int t0 = (int)floorf(s1);
    float f = s1 - (float)t0;
    float wa = 1.f - f, wb = f;
    bool ia = (t0 >= 0) && (t0 < HH);
    bool ib = ((t0 + 1) >= 0) && ((t0 + 1) < HH);
    float tw = (ia ? wa : 0.f) + (ib ? wb : 0.f);
    float na = ia ? (wa / tw) : 0.f;
    float nb = ib ? (wb / tw) : 0.f;
    int base; float A, B;
    if (t0 < 0) { base = 0; A = nb; B = 0.f; }
    else if (t0 >= HH - 1) { base = HH - 2; A = 0.f; B = na; }
    else { base = t0; A = na; B = nb; }
    P_I32(OFF_W1YT0)[r] = base;
    P_F32(OFF_W1YA)[r] = A;
    P_F32(OFF_W1YB)[r] = B;
  }
  for (int c = t; c < MW; c += 1024) {
    float s1 = ((float)c + 0.5f) * 0.25f - 0.5f;
    int t0 = (int)floorf(s1);
    float f = s1 - (float)t0;
    float wa = 1.f - f, wb = f;
    bool ia = (t0 >= 0) && (t0 < WW);
    bool ib = ((t0 + 1) >= 0) && ((t0 + 1) < WW);
    float tw = (ia ? wa : 0.f) + (ib ? wb : 0.f);
    float na = ia ? (wa / tw) : 0.f;
    float nb = ib ? (wb / tw) : 0.f;
    int base; float A, B;
    if (t0 < 0) { base = 0; A = nb; B = 0.f; }
    else if (t0 >= WW - 1) { base = WW - 2; A = 0.f; B = na; }
    else { base = t0; A = na; B = nb; }
    P_I32(OFF_W1XT0)[c] = base;
    P_F32(OFF_W1XA)[c] = A;
    P_F32(OFF_W1XB)[c] = B;
  }
  for (int o = t; o < OH; o += 1024) {
    const float inv = (float)(800.0 / 427.0);
    float s2 = ((float)o + 0.5f) * inv - 0.5f;
    int rA = (int)ceilf(s2 - inv);
    int rB = (int)floorf(s2 + inv);
    if (rA < 0) rA = 0;
    if (rB > MH - 1) rB = MH - 1;
    float tot = 0.f;
    for (int r = rA; r <= rB; r++) {
      float x = fabsf(s2 - (float)r) / inv;
      float w = 1.f - x; if (w < 0.f) w = 0.f;
      tot += w;
    }
    int base = rA; if (base > MH - 4) base = MH - 4;
    float o4[4] = {0.f, 0.f, 0.f, 0.f};
    for (int r = rA; r <= rB; r++) {
      float x = fabsf(s2 - (float)r) / inv;
      float w = 1.f - x; if (w < 0.f) w = 0.f;
      o4[r - base] += w / tot;
    }
    P_I32(OFF_W2YS)[o] = base;
    float* wp = P_F32(OFF_W2YW) + o * 4;
    wp[0] = o4[0]; wp[1] = o4[1]; wp[2] = o4[2]; wp[3] = o4[3];
  }
  for (int o = t; o < OW; o += 1024) {
    const float inv = (float)(1216.0 / 640.0);
    float s2 = ((float)o + 0.5f) * inv - 0.5f;
    int rA = (int)ceilf(s2 - inv);
    int rB = (int)floorf(s2 + inv);
    if (rA < 0) rA = 0;
    if (rB > MW - 1) rB = MW - 1;
    float tot = 0.f;
    for (int r = rA; r <= rB; r++) {
      float x = fabsf(s2 - (float)r) / inv;
      float w = 1.f - x; if (w < 0.f) w = 0.f;
      tot += w;
    }
    int base = rA; if (base > MW - 4) base = MW - 4;
    float o4[4] = {0.f, 0.f, 0.f, 0.f};
    for (int r = rA; r <= rB; r++) {
      float x = fabsf(s2 - (float)r) / inv;
      float w = 1.f - x; if (w < 0.f) w = 0.f;
      o4[r - base] += w / tot;
    }
    P_I32(OFF_W2XS)[o] = base;
    float* wp = P_F32(OFF_W2XW) + o * 4;
    wp[0] = o4[0]; wp[1] = o4[1]; wp[2] = o4[2]; wp[3] = o4[3];
  }
}

// -------- stage 2: word-major mask build, one candidate per THREAD --------
// float4 global staging (4x fewer VMEM issues); scalar swizzled LDS stores.
__global__ __launch_bounds__(256) void kmaskA(const float* __restrict__ segx, const float* __restrict__ segy,
                                              char* __restrict__ ws) {
  __shared__ float lx[128 * 64];
  __shared__ float ly[128 * 64];
  int w0 = blockIdx.x;
  int base = w0 << 6;
  int tid = threadIdx.x;
  for (int idx = tid; idx < 128 * 16; idx += 256) {
    int r = idx >> 4, q = (idx & 15) << 2;      // q = 0,4,..,60
    float4 vx = *(const float4*)(segx + (size_t)r * NPIX + base + q);
    float4 vy = *(const float4*)(segy + (size_t)r * NPIX + base + q);
    int rb = r << 6, rk = r & 63;
    lx[rb + ((q    ) ^ rk)] = vx.x;
    lx[rb + ((q + 1) ^ rk)] = vx.y;
    lx[rb + ((q + 2) ^ rk)] = vx.z;
    lx[rb + ((q + 3) ^ rk)] = vx.w;
    ly[rb + ((q    ) ^ rk)] = vy.x;
    ly[rb + ((q + 1) ^ rk)] = vy.y;
    ly[rb + ((q + 2) ^ rk)] = vy.z;
    ly[rb + ((q + 3) ^ rk)] = vy.w;
  }
  __syncthreads();
  const int* xind = P_I32(OFF_XIND);
  const int* yind = P_I32(OFF_YIND);
  u64* maskT = P_U64(OFF_MASKT) + (size_t)w0 * NPAD;
  double* partD = (double*)(ws + OFF_PARTD) + (size_t)w0 * NPAD;
  for (int c = tid; c < NPRE; c += 256) {
    int xi = xind[c], yi = yind[c];
    const float* rx = &lx[xi << 6];
    const float* ry = &ly[yi << 6];
    int xk = xi & 63, yk = yi & 63;
    u32 lo = 0, hi = 0;
    double sum = 0.0;
    #pragma unroll 8
    for (int p = 0; p < 32; p++) {
      float s = rx[p ^ xk] * ry[p ^ yk];
      if (s > M_THR) { lo |= (1u << p); sum += (double)s; }
    }
    #pragma unroll 8
    for (int p = 32; p < 64; p++) {
      float s = rx[p ^ xk] * ry[p ^ yk];
      if (s > M_THR) { hi |= (1u << (p - 32)); sum += (double)s; }
    }
    maskT[c] = (((u64)hi) << 32) | lo;     // coalesced: lanes -> consecutive c
    partD[c] = sum;
  }
}

// fused: blocks 0..499 = per-candidate reduction; blocks 500..619 = transpose
__global__ __launch_bounds__(256) void kmaskBT(char* __restrict__ ws) {
  __shared__ u64 tile[64][65];
  int b = blockIdx.x;
  int tid = threadIdx.x;
  if (b < NPRE) {
    __shared__ double cd[256];
    __shared__ int ci[256];
    int c = b;
    const u64* maskT = P_U64(OFF_MASKT);
    const double* partD = (const double*)(ws + OFF_PARTD);
    double ds = 0.0; int cnt = 0;
    for (int w = tid; w < NWORDS; w += 256) {
      ds += partD[(size_t)w * NPAD + c];
      cnt += (int)__popcll(maskT[(size_t)w * NPAD + c]);
    }
    cd[tid] = ds; ci[tid] = cnt;
    __syncthreads();
    for (int s2 = 128; s2 > 0; s2 >>= 1) {
      if (tid < s2) { ci[tid] += ci[tid + s2]; cd[tid] += cd[tid + s2]; }
      __syncthreads();
    }
    if (tid == 0) {
      float sm = (float)ci[0];
      float rawv = P_F32(OFF_RAW)[c];
      bool valid = rawv > S_THR;
      bool keep = valid && (sm > P_F32(OFF_STRIDE)[c]);
      float ssf = (float)cd[0];
      float segsc = ssf / fmaxf(sm, 1e-6f);
      P_F32(OFF_SCORE)[c] = keep ? (rawv * segsc) : 0.f;
      P_F32(OFF_SMF)[c] = keep ? sm : 0.f;
      P_I32(OFF_LABELK)[c] = keep ? P_I32(OFF_LABEL)[c] : -1;
    }
  } else {
    int q = b - NPRE;                 // 0..119 = 15 x 8 tiles
    int w0 = (q % 15) << 6;
    int c0 = (q / 15) << 6;
    const u64* maskT = P_U64(OFF_MASKT);
    for (int idx = tid; idx < 64 * 64; idx += 256) {
      int rw = idx >> 6, cc = idx & 63;
      int w = w0 + rw;
      tile[rw][cc] = (w < NWORDS) ? maskT[(size_t)w * NPAD + (c0 + cc)] : 0ull;
    }
    __syncthreads();
    u64* masks = P_U64(OFF_MASKS);
    for (int idx = tid; idx < 64 * 64; idx += 256) {
      int rc = idx >> 6, wwi = idx & 63;
      int c = c0 + rc, w = w0 + wwi;
      if (c < NPRE && w < NWORDS) masks[(size_t)c * MSTRIDE + w] = tile[wwi][rc];
    }
  }
}

// -------- stage 2 (fallback, candidate-major) if workspace is small --------
__global__ __launch_bounds__(256) void kmask(const float* __restrict__ segx, const float* __restrict__ segy,
                                             char* __restrict__ ws) {
  int c = blockIdx.x;
  int tid = threadIdx.x;
  int lane = tid & 63, wv = tid >> 6;
  const float* X = segx + (size_t)P_I32(OFF_XIND)[c] * NPIX;
  const float* Y = segy + (size_t)P_I32(OFF_YIND)[c] * NPIX;
  u64* mrow = P_U64(OFF_MASKS) + (size_t)c * MSTRIDE;
  int cnt = 0;
  double ssum = 0.0;
  for (int w0 = wv; w0 < NWORDS; w0 += 4) {
    int p = (w0 << 6) + lane;
    float s = X[p] * Y[p];
    bool b = s > M_THR;
    u64 bal = __ballot(b ? 1 : 0);
    if (lane == 0) mrow[w0] = bal;
    if (b) { cnt++; ssum += (double)s; }
  }
  __shared__ int ci[256];
  __shared__ double cd[256];
  ci[tid] = cnt; cd[tid] = ssum;
  __syncthreads();
  for (int s2 = 128; s2 > 0; s2 >>= 1) {
    if (tid < s2) { ci[tid] += ci[tid + s2]; cd[tid] += cd[tid + s2]; }
    __syncthreads();
  }
  if (tid == 0) {
    float sm = (float)ci[0];
    float rawv = P_F32(OFF_RAW)[c];
    bool valid = rawv > S_THR;
    bool keep = valid && (sm > P_F32(OFF_STRIDE)[c]);
    float ssf = (float)cd[0];
    float segsc = ssf / fmaxf(sm, 1e-6f);
    P_F32(OFF_SCORE)[c] = keep ? (rawv * segsc) : 0.f;
    P_F32(OFF_SMF)[c] = keep ? sm : 0.f;
    P_I32(OFF_LABELK)[c] = keep ? P_I32(OFF_LABEL)[c] : -1;
  }
}

// -------- stage 3+4: hybrid-bitonic descending sort + same-class pair list --------
__global__ __launch_bounds__(512) void ksp(char* __restrict__ ws) {
  __shared__ u64 sk[NPAD];
  __shared__ short slab[NPAD];
  __shared__ u32 scan[NPAD];
  int t = threadIdx.x;
  float sc = (t < NPRE) ? P_F32(OFF_SCORE)[t] : 0.f;
  u64 key = (((u64)__float_as_uint(sc)) << 32) | (u32)(NPAD - 1 - t);
  for (int k = 2; k <= NPAD; k <<= 1) {
    for (int j = k >> 1; j > 0; j >>= 1) {
      bool up = ((t & k) == 0);
      u64 other;
      if (j < 64) {
        other = shflx64(key, j);
      } else {
        sk[t] = key;
        __syncthreads();
        other = sk[t ^ j];
        __syncthreads();
      }
      bool takeMax = (((t & j) == 0) == up);
      key = takeMax ? (key > other ? key : other) : (key < other ? key : other);
    }
  }
  int ord = NPAD - 1 - (int)(key & 0xffffffffu);
  P_I32(OFF_ORDER)[t] = ord;
  P_F32(OFF_SSCORE)[t] = __uint_as_float((u32)(key >> 32));
  const int* labelK = P_I32(OFF_LABELK);
  int lab = (t < NPRE) ? labelK[ord] : -1;
  slab[t] = (short)lab;
  __syncthreads();
  u32 cnt = 0;
  if (lab >= 0) {
    short lj = (short)lab;
    for (int i = 0; i < t; i++) if (slab[i] == lj) cnt++;
  }
  scan[t] = cnt;
  __syncthreads();
  for (int off = 1; off < NPAD; off <<= 1) {
    u32 v = (t >= off) ? scan[t - off] : 0u;
    __syncthreads();
    scan[t] += v;
    __syncthreads();
  }
  if (t == NPAD - 1) {
    u32 tot = scan[t];
    P_U32(OFF_META)[4] = (tot > MAXPAIRS) ? MAXPAIRS : tot;
  }
  if (lab >= 0 && cnt) {
    u32 pos = scan[t] - cnt;
    short lj = (short)lab;
    u32* pairI = P_U32(OFF_PAIRI);
    for (int i = 0; i < t; i++) {
      if (slab[i] == lj) {
        if (pos < MAXPAIRS) pairI[pos] = (((u32)i) << 16) | (u32)t;
        pos++;
      }
    }
  }
}

__global__ __launch_bounds__(64) void kpiou(char* __restrict__ ws) {
  int P = (int)P_U32(OFF_META)[4]; if (P > MAXPAIRS) P = MAXPAIRS;
  const int* order = P_I32(OFF_ORDER);
  const float* smf = P_F32(OFF_SMF);
  const u64* masks = P_U64(OFF_MASKS);
  for (int p = blockIdx.x; p < P; p += gridDim.x) {
    u32 ij = P_U32(OFF_PAIRI)[p];
    int oi = order[ij >> 16];
    int oj = order[ij & 0xffffu];
    const u64* mi = masks + (size_t)oi * MSTRIDE;
    const u64* mj = masks + (size_t)oj * MSTRIDE;
    int inter = 0;
    for (int w = threadIdx.x; w < NWORDS; w += 64)
      inter += (int)__popcll(mi[w] & mj[w]);
    for (int off = 32; off > 0; off >>= 1)
      inter += __shfl_down(inter, off);
    if (threadIdx.x == 0) {
      float fi = (float)inter;
      float uni = (smf[oj] + smf[oi]) - fi;
      float iou = (uni > 0.f) ? (fi / fmaxf(uni, 1e-12f)) : 0.f;
      P_F32(OFF_PAIRIOU)[p] = iou;
    }
  }
}

// -------- stage 5: matrix-NMS decay + top-100 (hybrid bitonic) --------
__global__ __launch_bounds__(512) void knms(char* __restrict__ ws, float* __restrict__ out) {
  __shared__ int compI[NPAD];
  __shared__ int coefI[NPAD];
  __shared__ u64 sk[NPAD];
  int t = threadIdx.x;
  int P = (int)P_U32(OFF_META)[4]; if (P > MAXPAIRS) P = MAXPAIRS;
  const u32* pairI = P_U32(OFF_PAIRI);
  const float* pairIou = P_F32(OFF_PAIRIOU);
  const float* sscore = P_F32(OFF_SSCORE);
  const int* order = P_I32(OFF_ORDER);
  const int* labelK = P_I32(OFF_LABELK);
  int* topc = P_I32(OFF_TOPC);
  compI[t] = 0;
  coefI[t] = __float_as_int(1.0f);
  __syncthreads();
  for (int p = t; p < P; p += 512) {
    int j = (int)(pairI[p] & 0xffffu);
    atomicMax(&compI[j], __float_as_int(pairIou[p]));
  }
  __syncthreads();
  for (int p = t; p < P; p += 512) {
    u32 ij = pairI[p];
    int i = (int)(ij >> 16), j = (int)(ij & 0xffffu);
    float x = pairIou[p];
    float c = __int_as_float(compI[i]);
    float x2 = x * x, c2 = c * c;
    float r = (float)exp(-2.0 * ((double)x2 - (double)c2));
    atomicMin(&coefI[j], __float_as_int(r));
  }
  __syncthreads();
  float ns = 0.f;
  if (t < NPRE) {
    ns = sscore[t] * __int_as_float(coefI[t]);
    ns = (ns > U_THR) ? ns : 0.f;
  }
  u64 key = (((u64)__float_as_uint(ns)) << 32) | (u32)(NPAD - 1 - t);
  for (int k = 2; k <= NPAD; k <<= 1) {
    for (int j = k >> 1; j > 0; j >>= 1) {
      bool up = ((t & k) == 0);
      u64 other;
      if (j < 64) {
        other = shflx64(key, j);
      } else {
        sk[t] = key;
        __syncthreads();
        other = sk[t ^ j];
        __syncthreads();
      }
      bool takeMax = (((t & j) == 0) == up);
      key = takeMax ? (key > other ? key : other) : (key < other ? key : other);
    }
  }
  if (t < MAXOUT) {
    int pos = NPAD - 1 - (int)(key & 0xffffffffu);
    int cand = order[pos];
    topc[t] = cand;
    out[OUT_LBL + t] = (float)labelK[cand];
    out[OUT_SCR + t] = __uint_as_float((u32)(key >> 32));
  }
}

// -------- stage 7: fused double-resize + binarize; register stage-1 --------
__global__ __launch_bounds__(256) void kout(const float* __restrict__ segx, const float* __restrict__ segy,
                                            char* __restrict__ ws, float* __restrict__ out) {
  __shared__ float t1s[6][WW];   // y-interp mid rows
  __shared__ float yrs[2][MW];   // per-out-row y-contracted mid columns
  int flat = blockIdx.x;
  int w = (flat & 7) * 2675 + (flat >> 3);   // bijective XCD swizzle (21400 = 8*2675)
  int kk = w / NRBLK;
  int r2 = w - kk * NRBLK;
  int oy0 = r2 * ROWS_PER_BLK;
  int nrow = (oy0 + 1 < OH) ? 2 : 1;
  int tid = threadIdx.x;
  int cand = P_I32(OFF_TOPC)[kk];
  const float* X = segx + (size_t)P_I32(OFF_XIND)[cand] * NPIX;
  const float* Y = segy + (size_t)P_I32(OFF_YIND)[cand] * NPIX;
  const int* w2ys = P_I32(OFF_W2YS);
  int rb = w2ys[oy0];
  const int* w1yT0 = P_I32(OFF_W1YT0);
  const float* w1yA = P_F32(OFF_W1YA);
  const float* w1yB = P_F32(OFF_W1YB);
  int smin = w1yT0[rb];
  float Ay[6], By[6]; int i0a[6];
  #pragma unroll
  for (int mr = 0; mr < 6; mr++) {
    int r = rb + mr; if (r > MH - 1) r = MH - 1;
    i0a[mr] = w1yT0[r] - smin;
    Ay[mr] = w1yA[r];
    By[mr] = w1yB[r];
  }
  {
    int r0 = smin;     if (r0 > HH - 1) r0 = HH - 1;
    int r1 = smin + 1; if (r1 > HH - 1) r1 = HH - 1;
    int r2s = smin + 2; if (r2s > HH - 1) r2s = HH - 1;
    int r3 = smin + 3; if (r3 > HH - 1) r3 = HH - 1;
    const float* X0 = X + r0 * WW; const float* Y0 = Y + r0 * WW;
    const float* X1 = X + r1 * WW; const float* Y1 = Y + r1 * WW;
    const float* X2 = X + r2s * WW; const float* Y2 = Y + r2s * WW;
    const float* X3 = X + r3 * WW; const float* Y3 = Y + r3 * WW;
    for (int u = tid; u < WW; u += 256) {
      float s0 = X0[u] * Y0[u];
      float s1 = X1[u] * Y1[u];
      float s2 = X2[u] * Y2[u];
      float s3 = X3[u] * Y3[u];
      #pragma unroll
      for (int mr = 0; mr < 6; mr++) {
        int i0 = i0a[mr];
        float sa, sb;
        if (i0 == 0)      { sa = s0; sb = s1; }
        else if (i0 == 1) { sa = s1; sb = s2; }
        else              { sa = s2; sb = s3; }
        t1s[mr][u] = fmaf(By[mr], sb, Ay[mr] * sa);
      }
    }
  }
  __syncthreads();
  const int* w1xT0 = P_I32(OFF_W1XT0);
  const float* w1xA = P_F32(OFF_W1XA);
  const float* w1xB = P_F32(OFF_W1XB);
  float4 wy0 = *(const float4*)(P_F32(OFF_W2YW) + oy0 * 4);
  int oy1 = (nrow == 2) ? (oy0 + 1) : oy0;
  float4 wy1 = *(const float4*)(P_F32(OFF_W2YW) + oy1 * 4);
  int off1 = w2ys[oy1] - rb;
  for (int cc = tid; cc < MW; cc += 256) {
    int u0 = w1xT0[cc];
    float xa = w1xA[cc], xb = w1xB[cc];
    float up0 = fmaf(xb, t1s[0][u0 + 1], xa * t1s[0][u0]);
    float up1 = fmaf(xb, t1s[1][u0 + 1], xa * t1s[1][u0]);
    float up2 = fmaf(xb, t1s[2][u0 + 1], xa * t1s[2][u0]);
    float up3 = fmaf(xb, t1s[3][u0 + 1], xa * t1s[3][u0]);
    float up4 = fmaf(xb, t1s[4][u0 + 1], xa * t1s[4][u0]);
    float up5 = fmaf(xb, t1s[5][u0 + 1], xa * t1s[5][u0]);
    float v0 = wy0.x * up0;
    v0 = fmaf(wy0.y, up1, v0);
    v0 = fmaf(wy0.z, up2, v0);
    v0 = fmaf(wy0.w, up3, v0);
    yrs[0][cc] = v0;
    if (nrow == 2) {
      float a, b2, c3, d;
      if (off1 == 1)      { a = up1; b2 = up2; c3 = up3; d = up4; }
      else if (off1 == 2) { a = up2; b2 = up3; c3 = up4; d = up5; }
      else                { a = up0; b2 = up1; c3 = up2; d = up3; }
      float v1 = wy1.x * a;
      v1 = fmaf(wy1.y, b2, v1);
      v1 = fmaf(wy1.z, c3, v1);
      v1 = fmaf(wy1.w, d, v1);
      yrs[1][cc] = v1;
    }
  }
  __syncthreads();
  const int* w2xS = P_I32(OFF_W2XS);
  size_t ob0 = ((size_t)kk * OH + oy0) * OW;
  size_t ob1 = ob0 + OW;
  for (int ox = tid; ox < OW; ox += 256) {
    int cb = w2xS[ox];
    float4 wx = *(const float4*)(P_F32(OFF_W2XW) + ox * 4);
    float a0 = wx.x * yrs[0][cb];
    a0 = fmaf(wx.y, yrs[0][cb + 1], a0);
    a0 = fmaf(wx.z, yrs[0][cb + 2], a0);
    a0 = fmaf(wx.w, yrs[0][cb + 3], a0);
    out[ob0 + ox] = (a0 > M_THR) ? 1.0f : 0.0f;
    if (nrow == 2) {
      float a1 = wx.x * yrs[1][cb];
      a1 = fmaf(wx.y, yrs[1][cb + 1], a1);
      a1 = fmaf(wx.z, yrs[1][cb + 2], a1);
      a1 = fmaf(wx.w, yrs[1][cb + 3], a1);
      out[ob1 + ox] = (a1 > M_THR) ? 1.0f : 0.0f;
    }
  }
}

extern "C" void kernel_launch(void* const* d_in, const int* in_sizes, int n_in,
                              void* d_out, int out_size, void* d_ws, size_t ws_size,
                              hipStream_t stream) {
  (void)in_sizes; (void)n_in; (void)out_size;
  const float* cate = (const float*)d_in[0];
  const float* segx = (const float*)d_in[1];
  const float* segy = (const float*)d_in[2];
  char* ws = (char*)d_ws;
  float* out = (float*)d_out;
  const bool bigws = (ws_size >= (size_t)WS_NEED);   // constant per-session -> capture-safe

  hipMemsetAsync(ws, 0, ZERO_BYTES, stream);

  dim3 gFlat4((NFLAT / 4 + 255) / 256);
  hipLaunchKernelGGL(kh1, gFlat4, dim3(256), 0, stream, cate, ws);
  hipLaunchKernelGGL(kc1, dim3(1), dim3(1024), 0, stream, ws);
  hipLaunchKernelGGL(kg, gFlat4, dim3(256), 0, stream, cate, ws);
  hipLaunchKernelGGL(kselw, dim3(1), dim3(1024), 0, stream, ws);
  if (bigws) {
    hipLaunchKernelGGL(kmaskA, dim3(NWORDS), dim3(256), 0, stream, segx, segy, ws);
    hipLaunchKernelGGL(kmaskBT, dim3(NPRE + 120), dim3(256), 0, stream, ws);
  } else {
    hipLaunchKernelGGL(kmask, dim3(NPRE), dim3(256), 0, stream, segx, segy, ws);
  }
  hipLaunchKernelGGL(ksp, dim3(1), dim3(512), 0, stream, ws);
  hipLaunchKernelGGL(kpiou, dim3(2048), dim3(64), 0, stream, ws);
  hipLaunchKernelGGL(knms, dim3(1), dim3(512), 0, stream, ws, out);
  hipLaunchKernelGGL(kout, dim3(MAXOUT * NRBLK), dim3(256), 0, stream, segx, segy, ws, out);
}